// Round 2
// baseline (975.140 us; speedup 1.0000x reference)
//
#include <hip/hip_runtime.h>
#include <cstdint>

#define CO   64
#define CI   32
#define HH   56
#define WW   56
#define LL   3136        // 56*56
#define KK   288         // 32*9
#define NOUT 200704u     // 64*3136

// ---------- threefry2x32 cipher, exact JAX rotation/key schedule ----------
__host__ __device__ inline void tf2x32(uint32_t k0, uint32_t k1,
                                       uint32_t x0, uint32_t x1,
                                       uint32_t& o0, uint32_t& o1) {
  uint32_t ks2 = k0 ^ k1 ^ 0x1BD11BDAu;
  uint32_t v0 = x0 + k0, v1 = x1 + k1;
#define TF_R(r) { v0 += v1; v1 = (v1 << (r)) | (v1 >> (32 - (r))); v1 ^= v0; }
  TF_R(13) TF_R(15) TF_R(26) TF_R(6)
  v0 += k1;  v1 += ks2 + 1u;
  TF_R(17) TF_R(29) TF_R(16) TF_R(24)
  v0 += ks2; v1 += k0 + 2u;
  TF_R(13) TF_R(15) TF_R(26) TF_R(6)
  v0 += k0;  v1 += k1 + 3u;
  TF_R(17) TF_R(29) TF_R(16) TF_R(24)
  v0 += k1;  v1 += ks2 + 4u;
  TF_R(13) TF_R(15) TF_R(26) TF_R(6)
  v0 += ks2; v1 += k0 + 5u;
#undef TF_R
  o0 = v0; o1 = v1;
}

// partitionable-threefry random bits for flat index i (hi word of 64-bit iota = 0)
__device__ inline uint32_t rbits(uint32_t k0, uint32_t k1, uint32_t i) {
  uint32_t o0, o1;
  tf2x32(k0, k1, 0u, i, o0, o1);
  return o0 ^ o1;                 // bit_width=32: bits1 ^ bits2
}

// forward of _bitflip_fi for one element; ub = uniform bits, pb = pos bits
__device__ inline float fi_fwd(float x, float scale, uint32_t ub, uint32_t pb) {
#pragma clang fp contract(off)
  float q = rintf(x / scale);                    // round-half-even, IEEE div
  q = fminf(127.0f, fmaxf(-128.0f, q));
  uint32_t qt = ((uint32_t)(int)q) & 0xFFu;      // two's complement view
  float u = __uint_as_float((ub >> 9) | 0x3F800000u) - 1.0f;  // jax uniform
  uint32_t mask = (u < 0.008f) ? (1u << (pb & 7u)) : 0u;      // ber*bits
  uint32_t qf = qt ^ mask;
  float qs = (float)((qf >= 128u) ? (int)qf - 256 : (int)qf);
  float y = qs * scale;
  return x + (y - x);                            // x + stop_grad(y - x)
}

__device__ inline float block_max(float v) {
  __shared__ float s[256];
  int t = threadIdx.x;
  __syncthreads();                // protect reuse across calls
  s[t] = v; __syncthreads();
  for (int o = 128; o > 0; o >>= 1) {
    if (t < o) s[t] = fmaxf(s[t], s[t + o]);
    __syncthreads();
  }
  return s[0];
}

// ---------- kernel 1: quantize weights (_quant_ste forward) ----------
__global__ __launch_bounds__(256) void k_prep(const float* __restrict__ w,
                                              float* __restrict__ wq) {
#pragma clang fp contract(off)
  float m = 0.f;
  for (int i = threadIdx.x; i < CO * KK; i += 256) m = fmaxf(m, fabsf(w[i]));
  m = block_max(m);
  float scale = m / 127.0f + 1e-12f;
  for (int i = threadIdx.x; i < CO * KK; i += 256) {
    float xv = w[i];
    float q = fminf(127.0f, fmaxf(-128.0f, rintf(xv / scale)));
    float y = q * scale;
    wq[i] = xv + (y - xv);
  }
}

// ---------- kernel 2: max|p| = max_k (max_l|xc[l,k]| * max_co|wq[co,k]|) ----------
__global__ __launch_bounds__(256) void k_maxp(const float* __restrict__ x,
                                              const float* __restrict__ wq,
                                              unsigned int* __restrict__ maxp_bits) {
#pragma clang fp contract(off)
  int k = blockIdx.x;                       // 0..287
  int ci = k / 9, r = k % 9, di = r / 3, dj = r % 3;
  const float* xr = x + ci * LL;
  float mx = 0.f;
  for (int l = threadIdx.x; l < LL; l += 256) {
    int oy = l / WW, ox = l % WW;
    int yy = oy + di - 1, xx = ox + dj - 1;
    float v = (yy >= 0 && yy < HH && xx >= 0 && xx < WW) ? xr[yy * WW + xx] : 0.f;
    mx = fmaxf(mx, fabsf(v));
  }
  float mw = 0.f;
  for (int co = threadIdx.x; co < CO; co += 256) mw = fmaxf(mw, fabsf(wq[co * KK + k]));
  mx = block_max(mx);
  mw = block_max(mw);
  if (threadIdx.x == 0) atomicMax(maxp_bits, __float_as_uint(mx * mw));
}

// ---------- pass C: FI1 + cumsum, reduce max|c| ----------
__global__ __launch_bounds__(256) void k_passC(const float* __restrict__ x,
                                               const float* __restrict__ wq,
                                               const unsigned int* __restrict__ scal,
                                               unsigned int* __restrict__ maxc_bits,
                                               uint32_t ku0, uint32_t ku1,
                                               uint32_t kp0, uint32_t kp1) {
#pragma clang fp contract(off)
  __shared__ float sW[KK];
  int co = blockIdx.y;                      // 0..63
  for (int i = threadIdx.x; i < KK; i += 256) sW[i] = wq[co * KK + i];
  __syncthreads();
  int l = blockIdx.x * 256 + threadIdx.x;
  float maxc = 0.f;
  if (l < LL) {
    float scale_p = __uint_as_float(scal[1]) / 127.0f + 1e-12f;
    int oy = l / WW, ox = l % WW;
    uint32_t base = (uint32_t)(co * LL + l) * KK;
    float c = 0.f;
    int k = 0;
    for (int ci = 0; ci < CI; ++ci) {
      const float* xr = x + ci * LL;
#pragma unroll
      for (int di = 0; di < 3; ++di) {
        int yy = oy + di - 1;
        bool yok = (yy >= 0) && (yy < HH);
#pragma unroll
        for (int dj = 0; dj < 3; ++dj, ++k) {
          int xx = ox + dj - 1;
          float xv = (yok && xx >= 0 && xx < WW) ? xr[yy * WW + xx] : 0.f;
          float p = xv * sW[k];
          uint32_t i0 = base + (uint32_t)k;
          uint32_t ub = rbits(ku0, ku1, i0);
          uint32_t pb = rbits(kp0, kp1, i0);
          c += fi_fwd(p, scale_p, ub, pb);
          maxc = fmaxf(maxc, fabsf(c));
        }
      }
    }
  }
  maxc = block_max(maxc);
  if (threadIdx.x == 0) atomicMax(maxc_bits, __float_as_uint(maxc));
}

// ---------- pass D: FI1 + cumsum + FI2, build y, reduce max|y| ----------
__global__ __launch_bounds__(256) void k_passD(const float* __restrict__ x,
                                               const float* __restrict__ wq,
                                               const unsigned int* __restrict__ scal,
                                               unsigned int* __restrict__ maxy_bits,
                                               float* __restrict__ yout,
                                               uint32_t ku10, uint32_t ku11,
                                               uint32_t kp10, uint32_t kp11,
                                               uint32_t ku20, uint32_t ku21,
                                               uint32_t kp20, uint32_t kp21) {
#pragma clang fp contract(off)
  __shared__ float sW[KK];
  int co = blockIdx.y;
  for (int i = threadIdx.x; i < KK; i += 256) sW[i] = wq[co * KK + i];
  __syncthreads();
  int l = blockIdx.x * 256 + threadIdx.x;
  float maxy = 0.f;
  if (l < LL) {
    float scale_p = __uint_as_float(scal[1]) / 127.0f + 1e-12f;
    float scale_c = __uint_as_float(scal[2]) / 127.0f + 1e-12f;
    int oy = l / WW, ox = l % WW;
    uint32_t base = (uint32_t)(co * LL + l) * KK;
    float c = 0.f, e = 0.f, ys = 0.f;
    int k = 0;
    for (int ci = 0; ci < CI; ++ci) {
      const float* xr = x + ci * LL;
#pragma unroll
      for (int di = 0; di < 3; ++di) {
        int yy = oy + di - 1;
        bool yok = (yy >= 0) && (yy < HH);
#pragma unroll
        for (int dj = 0; dj < 3; ++dj, ++k) {
          int xx = ox + dj - 1;
          float xv = (yok && xx >= 0 && xx < WW) ? xr[yy * WW + xx] : 0.f;
          float p = xv * sW[k];
          uint32_t i0 = base + (uint32_t)k;
          uint32_t ub1 = rbits(ku10, ku11, i0);
          uint32_t pb1 = rbits(kp10, kp11, i0);
          c += fi_fwd(p, scale_p, ub1, pb1);
          uint32_t ub2 = rbits(ku20, ku21, i0);
          uint32_t pb2 = rbits(kp20, kp21, i0);
          float cf = fi_fwd(c, scale_c, ub2, pb2);
          if (k >= 1 && k <= 286) e += (cf - c);
          if (k == 287)           ys = cf;
        }
      }
    }
    float y = ys + e;
    yout[co * LL + l] = y;
    maxy = fabsf(y);
  }
  maxy = block_max(maxy);
  if (threadIdx.x == 0) atomicMax(maxy_bits, __float_as_uint(maxy));
}

// ---------- pass E: FI3 on y, in place in d_out ----------
__global__ __launch_bounds__(256) void k_passE(float* __restrict__ y,
                                               const unsigned int* __restrict__ scal,
                                               uint32_t ku0, uint32_t ku1,
                                               uint32_t kp0, uint32_t kp1) {
#pragma clang fp contract(off)
  uint32_t i = blockIdx.x * 256u + threadIdx.x;   // 0..NOUT-1 (grid exact)
  float scale_y = __uint_as_float(scal[3]) / 127.0f + 1e-12f;
  uint32_t ub = rbits(ku0, ku1, i);
  uint32_t pb = rbits(kp0, kp1, i);
  y[i] = fi_fwd(y[i], scale_y, ub, pb);
}

extern "C" void kernel_launch(void* const* d_in, const int* in_sizes, int n_in,
                              void* d_out, int out_size, void* d_ws, size_t ws_size,
                              hipStream_t stream) {
  const float* x = (const float*)d_in[0];   // (1,32,56,56)
  const float* w = (const float*)d_in[1];   // (64,32,3,3)
  float* out = (float*)d_out;               // (1,64,56,56)

  unsigned int* scal = (unsigned int*)d_ws; // [1]=max|p| [2]=max|c| [3]=max|y|
  float* wq = (float*)d_ws + 16;            // 18432 floats

  // ---- exact JAX key derivation, PARTITIONABLE threefry (default since 0.4.30+) ----
  // split(key, n): child i = full cipher output pair of counter (0, i)
  // random_bits(key, 32, shape): bits[i] = o0 ^ o1 of cipher(key, (0, i))
  uint32_t K1[2], K2[2], K3[2];
  tf2x32(0u, 42u, 0u, 0u, K1[0], K1[1]);    // split(key(42), 3)
  tf2x32(0u, 42u, 0u, 1u, K2[0], K2[1]);
  tf2x32(0u, 42u, 0u, 2u, K3[0], K3[1]);
  auto derive = [](const uint32_t kk[2], uint32_t U[2], uint32_t P[2]) {
    uint32_t kA0, kA1, kB0, kB1, t0, t1;
    tf2x32(kk[0], kk[1], 0u, 0u, kA0, kA1); // split(key,2)[0] -> uniform key
    tf2x32(kk[0], kk[1], 0u, 1u, kB0, kB1); // split(key,2)[1] -> randint key
    U[0] = kA0; U[1] = kA1;
    tf2x32(kB0, kB1, 0u, 1u, t0, t1);       // randint: _split(key)[1] -> lower_bits
    P[0] = t0; P[1] = t1;                   // (multiplier = (2^16 % 8)^2 % 8 = 0)
  };
  uint32_t U1[2],P1[2],U2[2],P2[2],U3[2],P3[2];
  derive(K1, U1, P1); derive(K2, U2, P2); derive(K3, U3, P3);

  hipMemsetAsync(d_ws, 0, 64, stream);      // zero the atomic-max slots

  k_prep<<<1, 256, 0, stream>>>(w, wq);
  k_maxp<<<KK, 256, 0, stream>>>(x, wq, scal + 1);
  dim3 g(13, 64);
  k_passC<<<g, 256, 0, stream>>>(x, wq, scal, scal + 2,
                                 U1[0], U1[1], P1[0], P1[1]);
  k_passD<<<g, 256, 0, stream>>>(x, wq, scal, scal + 3, out,
                                 U1[0], U1[1], P1[0], P1[1],
                                 U2[0], U2[1], P2[0], P2[1]);
  k_passE<<<NOUT / 256, 256, 0, stream>>>(out, scal,
                                          U3[0], U3[1], P3[0], P3[1]);
}

// Round 3
// 650.224 us; speedup vs baseline: 1.4997x; 1.4997x over previous
//
#include <hip/hip_runtime.h>
#include <cstdint>

#define CO   64
#define CI   32
#define HH   56
#define WW   56
#define LL   3136        // 56*56
#define KK   288         // 32*9
#define NOUT 200704u     // 64*3136
#define BER8 0.008f      // ber*bits, f32

// workspace layout: [0..63] atomic-max slots | 64.. wq (73728 B) | 81920.. c_ws
#define CWS_OFF_FLOATS 20480u                 // 81920 / 4
#define WS_NEED (81920ull + 4ull * 288ull * 200704ull)

// ---------- threefry2x32 cipher, exact JAX rotation/key schedule ----------
__host__ __device__ inline void tf2x32(uint32_t k0, uint32_t k1,
                                       uint32_t x0, uint32_t x1,
                                       uint32_t& o0, uint32_t& o1) {
  uint32_t ks2 = k0 ^ k1 ^ 0x1BD11BDAu;
  uint32_t v0 = x0 + k0, v1 = x1 + k1;
#define TF_R(r) { v0 += v1; v1 = (v1 << (r)) | (v1 >> (32 - (r))); v1 ^= v0; }
  TF_R(13) TF_R(15) TF_R(26) TF_R(6)
  v0 += k1;  v1 += ks2 + 1u;
  TF_R(17) TF_R(29) TF_R(16) TF_R(24)
  v0 += ks2; v1 += k0 + 2u;
  TF_R(13) TF_R(15) TF_R(26) TF_R(6)
  v0 += k0;  v1 += k1 + 3u;
  TF_R(17) TF_R(29) TF_R(16) TF_R(24)
  v0 += k1;  v1 += ks2 + 4u;
  TF_R(13) TF_R(15) TF_R(26) TF_R(6)
  v0 += ks2; v1 += k0 + 5u;
#undef TF_R
  o0 = v0; o1 = v1;
}

// partitionable-threefry random bits for flat index i (hi word of iota = 0)
__device__ inline uint32_t rbits(uint32_t k0, uint32_t k1, uint32_t i) {
  uint32_t o0, o1;
  tf2x32(k0, k1, 0u, i, o0, o1);
  return o0 ^ o1;
}

// FI forward with wave-level pos-cipher skip. Bit-identical to the reference:
// when mask==0 the int round-trip is the identity, so y = q*scale exactly.
__device__ inline float fi_fwd_skip(float x, float scale,
                                    uint32_t ub, uint32_t kp0, uint32_t kp1,
                                    uint32_t i0) {
#pragma clang fp contract(off)
  float q = rintf(x / scale);                    // round-half-even, IEEE div
  q = fminf(127.0f, fmaxf(-128.0f, q));
  float u = __uint_as_float((ub >> 9) | 0x3F800000u) - 1.0f;  // jax uniform
  bool flip = u < BER8;
  float y;
  if (__any(flip)) {                             // wave-uniform branch
    uint32_t pb = rbits(kp0, kp1, i0);
    uint32_t qt = ((uint32_t)(int)q) & 0xFFu;
    uint32_t mask = flip ? (1u << (pb & 7u)) : 0u;
    uint32_t qf = qt ^ mask;
    float qs = (float)((qf >= 128u) ? (int)qf - 256 : (int)qf);
    y = qs * scale;
  } else {
    y = q * scale;
  }
  return x + (y - x);                            // x + stop_grad(y - x)
}

__device__ inline float block_max(float v) {
  __shared__ float s[256];
  int t = threadIdx.x;
  __syncthreads();
  s[t] = v; __syncthreads();
  for (int o = 128; o > 0; o >>= 1) {
    if (t < o) s[t] = fmaxf(s[t], s[t + o]);
    __syncthreads();
  }
  return s[0];
}

// ---------- kernel 1: quantize weights (_quant_ste forward) ----------
__global__ __launch_bounds__(256) void k_prep(const float* __restrict__ w,
                                              float* __restrict__ wq) {
#pragma clang fp contract(off)
  float m = 0.f;
  for (int i = threadIdx.x; i < CO * KK; i += 256) m = fmaxf(m, fabsf(w[i]));
  m = block_max(m);
  float scale = m / 127.0f + 1e-12f;
  for (int i = threadIdx.x; i < CO * KK; i += 256) {
    float xv = w[i];
    float q = fminf(127.0f, fmaxf(-128.0f, rintf(xv / scale)));
    float y = q * scale;
    wq[i] = xv + (y - xv);
  }
}

// ---------- kernel 2: max|p| = max_k (max_l|xc[l,k]| * max_co|wq[co,k]|) ----------
__global__ __launch_bounds__(256) void k_maxp(const float* __restrict__ x,
                                              const float* __restrict__ wq,
                                              unsigned int* __restrict__ maxp_bits) {
#pragma clang fp contract(off)
  int k = blockIdx.x;                       // 0..287
  int ci = k / 9, r = k % 9, di = r / 3, dj = r % 3;
  const float* xr = x + ci * LL;
  float mx = 0.f;
  for (int l = threadIdx.x; l < LL; l += 256) {
    int oy = l / WW, ox = l % WW;
    int yy = oy + di - 1, xx = ox + dj - 1;
    float v = (yy >= 0 && yy < HH && xx >= 0 && xx < WW) ? xr[yy * WW + xx] : 0.f;
    mx = fmaxf(mx, fabsf(v));
  }
  float mw = 0.f;
  for (int co = threadIdx.x; co < CO; co += 256) mw = fmaxf(mw, fabsf(wq[co * KK + k]));
  mx = block_max(mx);
  mw = block_max(mw);
  if (threadIdx.x == 0) atomicMax(maxp_bits, __float_as_uint(mx * mw));
}

// ---------- pass C: FI1 + cumsum, reduce max|c|; optionally store c ----------
template <bool STORE>
__global__ __launch_bounds__(256) void k_passC(const float* __restrict__ x,
                                               const float* __restrict__ wq,
                                               const unsigned int* __restrict__ scal,
                                               unsigned int* __restrict__ maxc_bits,
                                               float* __restrict__ cws,
                                               uint32_t ku0, uint32_t ku1,
                                               uint32_t kp0, uint32_t kp1) {
#pragma clang fp contract(off)
  __shared__ float sW[KK];
  int co = blockIdx.y;                      // 0..63
  for (int i = threadIdx.x; i < KK; i += 256) sW[i] = wq[co * KK + i];
  __syncthreads();
  int l = blockIdx.x * 256 + threadIdx.x;
  float maxc = 0.f;
  if (l < LL) {
    float scale_p = __uint_as_float(scal[1]) / 127.0f + 1e-12f;
    int oy = l / WW, ox = l % WW;
    uint32_t outi = (uint32_t)(co * LL + l);
    uint32_t base = outi * KK;
    float c = 0.f;
    int k = 0;
    for (int ci = 0; ci < CI; ++ci) {
      const float* xr = x + ci * LL;
#pragma unroll
      for (int di = 0; di < 3; ++di) {
        int yy = oy + di - 1;
        bool yok = (yy >= 0) && (yy < HH);
#pragma unroll
        for (int dj = 0; dj < 3; ++dj, ++k) {
          int xx = ox + dj - 1;
          float xv = (yok && xx >= 0 && xx < WW) ? xr[yy * WW + xx] : 0.f;
          float p = xv * sW[k];
          uint32_t i0 = base + (uint32_t)k;
          uint32_t ub = rbits(ku0, ku1, i0);
          c += fi_fwd_skip(p, scale_p, ub, kp0, kp1, i0);
          if (STORE) cws[(uint32_t)k * NOUT + outi] = c;   // coalesced in l
          maxc = fmaxf(maxc, fabsf(c));
        }
      }
    }
  }
  maxc = block_max(maxc);
  if (threadIdx.x == 0) atomicMax(maxc_bits, __float_as_uint(maxc));
}

// ---------- pass D (fast): load stored c, FI2 only ----------
__global__ __launch_bounds__(256) void k_passD_load(const float* __restrict__ cws,
                                                    const unsigned int* __restrict__ scal,
                                                    unsigned int* __restrict__ maxy_bits,
                                                    float* __restrict__ yout,
                                                    uint32_t ku20, uint32_t ku21,
                                                    uint32_t kp20, uint32_t kp21) {
#pragma clang fp contract(off)
  int co = blockIdx.y;
  int l = blockIdx.x * 256 + threadIdx.x;
  float maxy = 0.f;
  if (l < LL) {
    float scale_c = __uint_as_float(scal[2]) / 127.0f + 1e-12f;
    uint32_t outi = (uint32_t)(co * LL + l);
    uint32_t base = outi * KK;
    float e = 0.f, ys = 0.f;
#pragma unroll 4
    for (int k = 0; k < KK; ++k) {
      float c = cws[(uint32_t)k * NOUT + outi];
      uint32_t i0 = base + (uint32_t)k;
      uint32_t ub2 = rbits(ku20, ku21, i0);
      float cf = fi_fwd_skip(c, scale_c, ub2, kp20, kp21, i0);
      if (k >= 1 && k <= 286) e += (cf - c);
      if (k == 287)           ys = cf;
    }
    float y = ys + e;
    yout[outi] = y;
    maxy = fabsf(y);
  }
  maxy = block_max(maxy);
  if (threadIdx.x == 0) atomicMax(maxy_bits, __float_as_uint(maxy));
}

// ---------- pass D (fallback): recompute FI1 + cumsum + FI2 ----------
__global__ __launch_bounds__(256) void k_passD_rec(const float* __restrict__ x,
                                                   const float* __restrict__ wq,
                                                   const unsigned int* __restrict__ scal,
                                                   unsigned int* __restrict__ maxy_bits,
                                                   float* __restrict__ yout,
                                                   uint32_t ku10, uint32_t ku11,
                                                   uint32_t kp10, uint32_t kp11,
                                                   uint32_t ku20, uint32_t ku21,
                                                   uint32_t kp20, uint32_t kp21) {
#pragma clang fp contract(off)
  __shared__ float sW[KK];
  int co = blockIdx.y;
  for (int i = threadIdx.x; i < KK; i += 256) sW[i] = wq[co * KK + i];
  __syncthreads();
  int l = blockIdx.x * 256 + threadIdx.x;
  float maxy = 0.f;
  if (l < LL) {
    float scale_p = __uint_as_float(scal[1]) / 127.0f + 1e-12f;
    float scale_c = __uint_as_float(scal[2]) / 127.0f + 1e-12f;
    int oy = l / WW, ox = l % WW;
    uint32_t base = (uint32_t)(co * LL + l) * KK;
    float c = 0.f, e = 0.f, ys = 0.f;
    int k = 0;
    for (int ci = 0; ci < CI; ++ci) {
      const float* xr = x + ci * LL;
#pragma unroll
      for (int di = 0; di < 3; ++di) {
        int yy = oy + di - 1;
        bool yok = (yy >= 0) && (yy < HH);
#pragma unroll
        for (int dj = 0; dj < 3; ++dj, ++k) {
          int xx = ox + dj - 1;
          float xv = (yok && xx >= 0 && xx < WW) ? xr[yy * WW + xx] : 0.f;
          float p = xv * sW[k];
          uint32_t i0 = base + (uint32_t)k;
          uint32_t ub1 = rbits(ku10, ku11, i0);
          c += fi_fwd_skip(p, scale_p, ub1, kp10, kp11, i0);
          uint32_t ub2 = rbits(ku20, ku21, i0);
          float cf = fi_fwd_skip(c, scale_c, ub2, kp20, kp21, i0);
          if (k >= 1 && k <= 286) e += (cf - c);
          if (k == 287)           ys = cf;
        }
      }
    }
    float y = ys + e;
    yout[co * LL + l] = y;
    maxy = fabsf(y);
  }
  maxy = block_max(maxy);
  if (threadIdx.x == 0) atomicMax(maxy_bits, __float_as_uint(maxy));
}

// ---------- pass E: FI3 on y, in place in d_out ----------
__global__ __launch_bounds__(256) void k_passE(float* __restrict__ y,
                                               const unsigned int* __restrict__ scal,
                                               uint32_t ku0, uint32_t ku1,
                                               uint32_t kp0, uint32_t kp1) {
#pragma clang fp contract(off)
  uint32_t i = blockIdx.x * 256u + threadIdx.x;
  float scale_y = __uint_as_float(scal[3]) / 127.0f + 1e-12f;
  uint32_t ub = rbits(ku0, ku1, i);
  y[i] = fi_fwd_skip(y[i], scale_y, ub, kp0, kp1, i);
}

extern "C" void kernel_launch(void* const* d_in, const int* in_sizes, int n_in,
                              void* d_out, int out_size, void* d_ws, size_t ws_size,
                              hipStream_t stream) {
  const float* x = (const float*)d_in[0];   // (1,32,56,56)
  const float* w = (const float*)d_in[1];   // (64,32,3,3)
  float* out = (float*)d_out;               // (1,64,56,56)

  unsigned int* scal = (unsigned int*)d_ws; // [1]=max|p| [2]=max|c| [3]=max|y|
  float* wq = (float*)d_ws + 16;            // 18432 floats
  float* cws = (float*)d_ws + CWS_OFF_FLOATS;
  bool bigws = ws_size >= WS_NEED;          // constant across calls -> graph-safe

  // ---- exact JAX key derivation, partitionable threefry ----
  uint32_t K1[2], K2[2], K3[2];
  tf2x32(0u, 42u, 0u, 0u, K1[0], K1[1]);    // split(key(42), 3)
  tf2x32(0u, 42u, 0u, 1u, K2[0], K2[1]);
  tf2x32(0u, 42u, 0u, 2u, K3[0], K3[1]);
  auto derive = [](const uint32_t kk[2], uint32_t U[2], uint32_t P[2]) {
    uint32_t kA0, kA1, kB0, kB1, t0, t1;
    tf2x32(kk[0], kk[1], 0u, 0u, kA0, kA1); // split(key,2)[0] -> uniform key
    tf2x32(kk[0], kk[1], 0u, 1u, kB0, kB1); // split(key,2)[1] -> randint key
    U[0] = kA0; U[1] = kA1;
    tf2x32(kB0, kB1, 0u, 1u, t0, t1);       // randint lower-bits key
    P[0] = t0; P[1] = t1;
  };
  uint32_t U1[2],P1[2],U2[2],P2[2],U3[2],P3[2];
  derive(K1, U1, P1); derive(K2, U2, P2); derive(K3, U3, P3);

  hipMemsetAsync(d_ws, 0, 64, stream);      // zero the atomic-max slots

  k_prep<<<1, 256, 0, stream>>>(w, wq);
  k_maxp<<<KK, 256, 0, stream>>>(x, wq, scal + 1);
  dim3 g(13, 64);
  if (bigws) {
    k_passC<true><<<g, 256, 0, stream>>>(x, wq, scal, scal + 2, cws,
                                         U1[0], U1[1], P1[0], P1[1]);
    k_passD_load<<<g, 256, 0, stream>>>(cws, scal, scal + 3, out,
                                        U2[0], U2[1], P2[0], P2[1]);
  } else {
    k_passC<false><<<g, 256, 0, stream>>>(x, wq, scal, scal + 2, cws,
                                          U1[0], U1[1], P1[0], P1[1]);
    k_passD_rec<<<g, 256, 0, stream>>>(x, wq, scal, scal + 3, out,
                                       U1[0], U1[1], P1[0], P1[1],
                                       U2[0], U2[1], P2[0], P2[1]);
  }
  k_passE<<<NOUT / 256, 256, 0, stream>>>(out, scal,
                                          U3[0], U3[1], P3[0], P3[1]);
}

// Round 4
// 585.831 us; speedup vs baseline: 1.6645x; 1.1099x over previous
//
#include <hip/hip_runtime.h>
#include <cstdint>

#define CO   64
#define CI   32
#define HH   56
#define WW   56
#define LL   3136        // 56*56
#define KK   288         // 32*9
#define NOUT 200704u     // 64*3136
#define BER8 0.008f      // ber*bits, f32
#define KG   4           // k-groups per output element in passD
#define KCH  72          // 288 / KG

// workspace layout: [0..63] atomic-max slots | 64.. wq (73728 B) | 81920.. c_ws
#define CWS_OFF_FLOATS 20480u                 // 81920 / 4
#define WS_NEED (81920ull + 4ull * 288ull * 200704ull)

// ---------- threefry2x32 cipher, exact JAX rotation/key schedule ----------
__host__ __device__ inline void tf2x32(uint32_t k0, uint32_t k1,
                                       uint32_t x0, uint32_t x1,
                                       uint32_t& o0, uint32_t& o1) {
  uint32_t ks2 = k0 ^ k1 ^ 0x1BD11BDAu;
  uint32_t v0 = x0 + k0, v1 = x1 + k1;
#define TF_R(r) { v0 += v1; v1 = (v1 << (r)) | (v1 >> (32 - (r))); v1 ^= v0; }
  TF_R(13) TF_R(15) TF_R(26) TF_R(6)
  v0 += k1;  v1 += ks2 + 1u;
  TF_R(17) TF_R(29) TF_R(16) TF_R(24)
  v0 += ks2; v1 += k0 + 2u;
  TF_R(13) TF_R(15) TF_R(26) TF_R(6)
  v0 += k0;  v1 += k1 + 3u;
  TF_R(17) TF_R(29) TF_R(16) TF_R(24)
  v0 += k1;  v1 += ks2 + 4u;
  TF_R(13) TF_R(15) TF_R(26) TF_R(6)
  v0 += ks2; v1 += k0 + 5u;
#undef TF_R
  o0 = v0; o1 = v1;
}

// partitionable-threefry random bits for flat index i (hi word of iota = 0)
__device__ inline uint32_t rbits(uint32_t k0, uint32_t k1, uint32_t i) {
  uint32_t o0, o1;
  tf2x32(k0, k1, 0u, i, o0, o1);
  return o0 ^ o1;
}

// FI forward with wave-level pos-cipher skip. Bit-identical to the reference:
// when mask==0 the int round-trip is the identity, so y = q*scale exactly.
__device__ inline float fi_fwd_skip(float x, float scale,
                                    uint32_t ub, uint32_t kp0, uint32_t kp1,
                                    uint32_t i0) {
#pragma clang fp contract(off)
  float q = rintf(x / scale);                    // round-half-even, IEEE div
  q = fminf(127.0f, fmaxf(-128.0f, q));
  float u = __uint_as_float((ub >> 9) | 0x3F800000u) - 1.0f;  // jax uniform
  bool flip = u < BER8;
  float y;
  if (__any(flip)) {                             // wave-uniform branch
    uint32_t pb = rbits(kp0, kp1, i0);
    uint32_t qt = ((uint32_t)(int)q) & 0xFFu;
    uint32_t mask = flip ? (1u << (pb & 7u)) : 0u;
    uint32_t qf = qt ^ mask;
    float qs = (float)((qf >= 128u) ? (int)qf - 256 : (int)qf);
    y = qs * scale;
  } else {
    y = q * scale;
  }
  return x + (y - x);                            // x + stop_grad(y - x)
}

template <int BS>
__device__ inline float block_max(float v) {
  __shared__ float s[BS];
  int t = threadIdx.x;
  __syncthreads();
  s[t] = v; __syncthreads();
  for (int o = BS / 2; o > 0; o >>= 1) {
    if (t < o) s[t] = fmaxf(s[t], s[t + o]);
    __syncthreads();
  }
  return s[0];
}

// ---------- kernel 1: quantize weights (_quant_ste forward) ----------
__global__ __launch_bounds__(256) void k_prep(const float* __restrict__ w,
                                              float* __restrict__ wq) {
#pragma clang fp contract(off)
  float m = 0.f;
  for (int i = threadIdx.x; i < CO * KK; i += 256) m = fmaxf(m, fabsf(w[i]));
  m = block_max<256>(m);
  float scale = m / 127.0f + 1e-12f;
  for (int i = threadIdx.x; i < CO * KK; i += 256) {
    float xv = w[i];
    float q = fminf(127.0f, fmaxf(-128.0f, rintf(xv / scale)));
    float y = q * scale;
    wq[i] = xv + (y - xv);
  }
}

// ---------- kernel 2: max|p| = max_k (max_l|xc[l,k]| * max_co|wq[co,k]|) ----------
__global__ __launch_bounds__(256) void k_maxp(const float* __restrict__ x,
                                              const float* __restrict__ wq,
                                              unsigned int* __restrict__ maxp_bits) {
#pragma clang fp contract(off)
  int k = blockIdx.x;                       // 0..287
  int ci = k / 9, r = k % 9, di = r / 3, dj = r % 3;
  const float* xr = x + ci * LL;
  float mx = 0.f;
  for (int l = threadIdx.x; l < LL; l += 256) {
    int oy = l / WW, ox = l % WW;
    int yy = oy + di - 1, xx = ox + dj - 1;
    float v = (yy >= 0 && yy < HH && xx >= 0 && xx < WW) ? xr[yy * WW + xx] : 0.f;
    mx = fmaxf(mx, fabsf(v));
  }
  float mw = 0.f;
  for (int co = threadIdx.x; co < CO; co += 256) mw = fmaxf(mw, fabsf(wq[co * KK + k]));
  mx = block_max<256>(mx);
  mw = block_max<256>(mw);
  if (threadIdx.x == 0) atomicMax(maxp_bits, __float_as_uint(mx * mw));
}

// ---------- pass C: FI1 + sequential cumsum (bit-exact left fold), store c ----------
// 64-thread blocks for dispatch balance: grid 49x64 = 3136 single-wave blocks.
template <bool STORE>
__global__ __launch_bounds__(64) void k_passC(const float* __restrict__ x,
                                              const float* __restrict__ wq,
                                              const unsigned int* __restrict__ scal,
                                              unsigned int* __restrict__ maxc_bits,
                                              float* __restrict__ cws,
                                              uint32_t ku0, uint32_t ku1,
                                              uint32_t kp0, uint32_t kp1) {
#pragma clang fp contract(off)
  __shared__ float sW[KK];
  int co = blockIdx.y;                      // 0..63
  for (int i = threadIdx.x; i < KK; i += 64) sW[i] = wq[co * KK + i];
  __syncthreads();
  int l = blockIdx.x * 64 + threadIdx.x;
  float maxc = 0.f;
  if (l < LL) {
    float scale_p = __uint_as_float(scal[1]) / 127.0f + 1e-12f;
    int oy = l / WW, ox = l % WW;
    uint32_t outi = (uint32_t)(co * LL + l);
    uint32_t base = outi * KK;
    float c = 0.f;
    int k = 0;
    for (int ci = 0; ci < CI; ++ci) {
      const float* xr = x + ci * LL;
#pragma unroll
      for (int di = 0; di < 3; ++di) {
        int yy = oy + di - 1;
        bool yok = (yy >= 0) && (yy < HH);
#pragma unroll
        for (int dj = 0; dj < 3; ++dj, ++k) {
          int xx = ox + dj - 1;
          float xv = (yok && xx >= 0 && xx < WW) ? xr[yy * WW + xx] : 0.f;
          float p = xv * sW[k];
          uint32_t i0 = base + (uint32_t)k;
          uint32_t ub = rbits(ku0, ku1, i0);
          c += fi_fwd_skip(p, scale_p, ub, kp0, kp1, i0);
          if (STORE) cws[(uint32_t)k * NOUT + outi] = c;   // coalesced in l
          maxc = fmaxf(maxc, fabsf(c));
        }
      }
    }
  }
  maxc = block_max<64>(maxc);
  if (threadIdx.x == 0) atomicMax(maxc_bits, __float_as_uint(maxc));
}

// ---------- pass D (fast): in-block k-split, FI2 only, deterministic merge ----------
// Block = 4 waves; wave kg handles k in [kg*72, kg*72+72) for 64 consecutive outi.
// k=0's cf is unused by the reference (e covers 1..286, ys = k=287) -> skipped.
__global__ __launch_bounds__(256) void k_passD_split(const float* __restrict__ cws,
                                                     const unsigned int* __restrict__ scal,
                                                     unsigned int* __restrict__ maxy_bits,
                                                     float* __restrict__ yout,
                                                     uint32_t ku0, uint32_t ku1,
                                                     uint32_t kp0, uint32_t kp1) {
#pragma clang fp contract(off)
  __shared__ float sE[KG][64];
  __shared__ float sYs[64];
  int tid = threadIdx.x;
  int lane = tid & 63;
  int kg = tid >> 6;                               // 0..3
  uint32_t outi = blockIdx.x * 64u + (uint32_t)lane;   // 3136*64 = NOUT exact
  float scale_c = __uint_as_float(scal[2]) / 127.0f + 1e-12f;
  int ks = (kg == 0) ? 1 : kg * KCH;
  int ke = (kg == KG - 1) ? (KK - 1) : (kg * KCH + KCH);
  const float* cp = cws + (uint32_t)ks * NOUT + outi;
  uint32_t i0 = outi * (uint32_t)KK + (uint32_t)ks;
  float e = 0.f;
#pragma unroll 4
  for (int k = ks; k < ke; ++k) {
    float c = *cp; cp += NOUT;
    uint32_t ub = rbits(ku0, ku1, i0);
    float cf = fi_fwd_skip(c, scale_c, ub, kp0, kp1, i0);
    e += (cf - c);
    ++i0;
  }
  sE[kg][lane] = e;
  if (kg == KG - 1) {                              // k = 287 -> ys
    float c = *cp;
    uint32_t ub = rbits(ku0, ku1, i0);
    float cf = fi_fwd_skip(c, scale_c, ub, kp0, kp1, i0);
    sYs[lane] = cf;
  }
  __syncthreads();
  float maxy = 0.f;
  if (tid < 64) {
    float ee = ((sE[0][lane] + sE[1][lane]) + sE[2][lane]) + sE[3][lane];
    float y = sYs[lane] + ee;
    yout[outi] = y;
    maxy = fabsf(y);
  }
  maxy = block_max<256>(maxy);
  if (tid == 0) atomicMax(maxy_bits, __float_as_uint(maxy));
}

// ---------- pass D (fallback, small ws): recompute FI1 + cumsum + FI2 ----------
__global__ __launch_bounds__(256) void k_passD_rec(const float* __restrict__ x,
                                                   const float* __restrict__ wq,
                                                   const unsigned int* __restrict__ scal,
                                                   unsigned int* __restrict__ maxy_bits,
                                                   float* __restrict__ yout,
                                                   uint32_t ku10, uint32_t ku11,
                                                   uint32_t kp10, uint32_t kp11,
                                                   uint32_t ku20, uint32_t ku21,
                                                   uint32_t kp20, uint32_t kp21) {
#pragma clang fp contract(off)
  __shared__ float sW[KK];
  int co = blockIdx.y;
  for (int i = threadIdx.x; i < KK; i += 256) sW[i] = wq[co * KK + i];
  __syncthreads();
  int l = blockIdx.x * 256 + threadIdx.x;
  float maxy = 0.f;
  if (l < LL) {
    float scale_p = __uint_as_float(scal[1]) / 127.0f + 1e-12f;
    float scale_c = __uint_as_float(scal[2]) / 127.0f + 1e-12f;
    int oy = l / WW, ox = l % WW;
    uint32_t base = (uint32_t)(co * LL + l) * KK;
    float c = 0.f, e = 0.f, ys = 0.f;
    int k = 0;
    for (int ci = 0; ci < CI; ++ci) {
      const float* xr = x + ci * LL;
#pragma unroll
      for (int di = 0; di < 3; ++di) {
        int yy = oy + di - 1;
        bool yok = (yy >= 0) && (yy < HH);
#pragma unroll
        for (int dj = 0; dj < 3; ++dj, ++k) {
          int xx = ox + dj - 1;
          float xv = (yok && xx >= 0 && xx < WW) ? xr[yy * WW + xx] : 0.f;
          float p = xv * sW[k];
          uint32_t i0 = base + (uint32_t)k;
          uint32_t ub1 = rbits(ku10, ku11, i0);
          c += fi_fwd_skip(p, scale_p, ub1, kp10, kp11, i0);
          uint32_t ub2 = rbits(ku20, ku21, i0);
          float cf = fi_fwd_skip(c, scale_c, ub2, kp20, kp21, i0);
          if (k >= 1 && k <= 286) e += (cf - c);
          if (k == 287)           ys = cf;
        }
      }
    }
    float y = ys + e;
    yout[co * LL + l] = y;
    maxy = fabsf(y);
  }
  maxy = block_max<256>(maxy);
  if (threadIdx.x == 0) atomicMax(maxy_bits, __float_as_uint(maxy));
}

// ---------- pass E: FI3 on y, in place in d_out ----------
__global__ __launch_bounds__(256) void k_passE(float* __restrict__ y,
                                               const unsigned int* __restrict__ scal,
                                               uint32_t ku0, uint32_t ku1,
                                               uint32_t kp0, uint32_t kp1) {
#pragma clang fp contract(off)
  uint32_t i = blockIdx.x * 256u + threadIdx.x;
  float scale_y = __uint_as_float(scal[3]) / 127.0f + 1e-12f;
  uint32_t ub = rbits(ku0, ku1, i);
  y[i] = fi_fwd_skip(y[i], scale_y, ub, kp0, kp1, i);
}

extern "C" void kernel_launch(void* const* d_in, const int* in_sizes, int n_in,
                              void* d_out, int out_size, void* d_ws, size_t ws_size,
                              hipStream_t stream) {
  const float* x = (const float*)d_in[0];   // (1,32,56,56)
  const float* w = (const float*)d_in[1];   // (64,32,3,3)
  float* out = (float*)d_out;               // (1,64,56,56)

  unsigned int* scal = (unsigned int*)d_ws; // [1]=max|p| [2]=max|c| [3]=max|y|
  float* wq = (float*)d_ws + 16;            // 18432 floats
  float* cws = (float*)d_ws + CWS_OFF_FLOATS;
  bool bigws = ws_size >= WS_NEED;          // constant across calls -> graph-safe

  // ---- exact JAX key derivation, partitionable threefry ----
  uint32_t K1[2], K2[2], K3[2];
  tf2x32(0u, 42u, 0u, 0u, K1[0], K1[1]);    // split(key(42), 3)
  tf2x32(0u, 42u, 0u, 1u, K2[0], K2[1]);
  tf2x32(0u, 42u, 0u, 2u, K3[0], K3[1]);
  auto derive = [](const uint32_t kk[2], uint32_t U[2], uint32_t P[2]) {
    uint32_t kA0, kA1, kB0, kB1, t0, t1;
    tf2x32(kk[0], kk[1], 0u, 0u, kA0, kA1); // split(key,2)[0] -> uniform key
    tf2x32(kk[0], kk[1], 0u, 1u, kB0, kB1); // split(key,2)[1] -> randint key
    U[0] = kA0; U[1] = kA1;
    tf2x32(kB0, kB1, 0u, 1u, t0, t1);       // randint lower-bits key
    P[0] = t0; P[1] = t1;
  };
  uint32_t U1[2],P1[2],U2[2],P2[2],U3[2],P3[2];
  derive(K1, U1, P1); derive(K2, U2, P2); derive(K3, U3, P3);

  hipMemsetAsync(d_ws, 0, 64, stream);      // zero the atomic-max slots

  k_prep<<<1, 256, 0, stream>>>(w, wq);
  k_maxp<<<KK, 256, 0, stream>>>(x, wq, scal + 1);
  dim3 gC(49, 64);                          // 64-thread blocks: 3136 blocks
  if (bigws) {
    k_passC<true><<<gC, 64, 0, stream>>>(x, wq, scal, scal + 2, cws,
                                         U1[0], U1[1], P1[0], P1[1]);
    k_passD_split<<<3136, 256, 0, stream>>>(cws, scal, scal + 3, out,
                                            U2[0], U2[1], P2[0], P2[1]);
  } else {
    k_passC<false><<<gC, 64, 0, stream>>>(x, wq, scal, scal + 2, cws,
                                          U1[0], U1[1], P1[0], P1[1]);
    dim3 gR(13, 64);
    k_passD_rec<<<gR, 256, 0, stream>>>(x, wq, scal, scal + 3, out,
                                        U1[0], U1[1], P1[0], P1[1],
                                        U2[0], U2[1], P2[0], P2[1]);
  }
  k_passE<<<NOUT / 256, 256, 0, stream>>>(out, scal,
                                          U3[0], U3[1], P3[0], P3[1]);
}

// Round 5
// 573.169 us; speedup vs baseline: 1.7013x; 1.0221x over previous
//
#include <hip/hip_runtime.h>
#include <cstdint>

#define CO   64
#define CI   32
#define HH   56
#define WW   56
#define LL   3136        // 56*56
#define KK   288         // 32*9
#define NOUT 200704u     // 64*3136
#define KG   4           // k-groups per output element in fi2
#define KCH  72          // 288 / KG
#define KPT  4           // k's per thread in fi1

// flip threshold: u < 0.008f  <=>  (ub>>9) <= 67108  <=>  ub < 67109*512
#define FLIP_LT 34359808u

// workspace layout: [0..63] atomic-max slots | 64.. wq (73728 B) | 81920.. c_ws
// c_ws is used in place: k_fi1 writes p, k_cumsum transforms p -> c in situ.
#define CWS_OFF_FLOATS 20480u                 // 81920 / 4
#define WS_NEED (81920ull + 4ull * 288ull * 200704ull)

__host__ __device__ inline uint32_t rotl32(uint32_t v, uint32_t r) {
#ifdef __HIP_DEVICE_COMPILE__
  return __builtin_amdgcn_alignbit(v, v, 32u - r);   // (v:v)>>(32-r) = rotl(v,r)
#else
  return (v << r) | (v >> (32u - r));
#endif
}

// ---------- threefry2x32 cipher, exact JAX rotation/key schedule ----------
__host__ __device__ inline void tf2x32(uint32_t k0, uint32_t k1,
                                       uint32_t x0, uint32_t x1,
                                       uint32_t& o0, uint32_t& o1) {
  uint32_t ks2 = k0 ^ k1 ^ 0x1BD11BDAu;
  uint32_t v0 = x0 + k0, v1 = x1 + k1;
#define TF_R(r) { v0 += v1; v1 = rotl32(v1, r); v1 ^= v0; }
  TF_R(13) TF_R(15) TF_R(26) TF_R(6)
  v0 += k1;  v1 += ks2 + 1u;
  TF_R(17) TF_R(29) TF_R(16) TF_R(24)
  v0 += ks2; v1 += k0 + 2u;
  TF_R(13) TF_R(15) TF_R(26) TF_R(6)
  v0 += k0;  v1 += k1 + 3u;
  TF_R(17) TF_R(29) TF_R(16) TF_R(24)
  v0 += k1;  v1 += ks2 + 4u;
  TF_R(13) TF_R(15) TF_R(26) TF_R(6)
  v0 += ks2; v1 += k0 + 5u;
#undef TF_R
  o0 = v0; o1 = v1;
}

// partitionable-threefry random bits for flat index i (hi word of iota = 0)
__device__ inline uint32_t rbits(uint32_t k0, uint32_t k1, uint32_t i) {
  uint32_t o0, o1;
  tf2x32(k0, k1, 0u, i, o0, o1);
  return o0 ^ o1;
}

// FI forward with wave-level pos-cipher skip. Bit-identical to the reference:
// integer flip test proven equal to the f32 compare; mask==0 int round-trip
// is the identity, so the skip path y = q*scale is exact.
__device__ inline float fi_fwd_skip(float x, float scale,
                                    uint32_t ub, uint32_t kp0, uint32_t kp1,
                                    uint32_t i0) {
#pragma clang fp contract(off)
  float q = rintf(x / scale);                    // round-half-even, IEEE div
  q = fminf(127.0f, fmaxf(-128.0f, q));
  bool flip = ub < FLIP_LT;
  float y;
  if (__any(flip)) {                             // wave-uniform branch
    uint32_t pb = rbits(kp0, kp1, i0);
    uint32_t qt = ((uint32_t)(int)q) & 0xFFu;
    uint32_t mask = flip ? (1u << (pb & 7u)) : 0u;
    uint32_t qf = qt ^ mask;
    float qs = (float)((qf >= 128u) ? (int)qf - 256 : (int)qf);
    y = qs * scale;
  } else {
    y = q * scale;
  }
  return x + (y - x);                            // x + stop_grad(y - x)
}

template <int BS>
__device__ inline float block_max(float v) {
  __shared__ float s[BS];
  int t = threadIdx.x;
  __syncthreads();
  s[t] = v; __syncthreads();
  for (int o = BS / 2; o > 0; o >>= 1) {
    if (t < o) s[t] = fmaxf(s[t], s[t + o]);
    __syncthreads();
  }
  return s[0];
}

// ---------- kernel 1: quantize weights (_quant_ste forward) ----------
__global__ __launch_bounds__(256) void k_prep(const float* __restrict__ w,
                                              float* __restrict__ wq) {
#pragma clang fp contract(off)
  float m = 0.f;
  for (int i = threadIdx.x; i < CO * KK; i += 256) m = fmaxf(m, fabsf(w[i]));
  m = block_max<256>(m);
  float scale = m / 127.0f + 1e-12f;
  for (int i = threadIdx.x; i < CO * KK; i += 256) {
    float xv = w[i];
    float q = fminf(127.0f, fmaxf(-128.0f, rintf(xv / scale)));
    float y = q * scale;
    wq[i] = xv + (y - xv);
  }
}

// ---------- kernel 2: max|p| = max_k (max_l|xc[l,k]| * max_co|wq[co,k]|) ----------
__global__ __launch_bounds__(256) void k_maxp(const float* __restrict__ x,
                                              const float* __restrict__ wq,
                                              unsigned int* __restrict__ maxp_bits) {
#pragma clang fp contract(off)
  int k = blockIdx.x;                       // 0..287
  int ci = k / 9, r = k % 9, di = r / 3, dj = r % 3;
  const float* xr = x + ci * LL;
  float mx = 0.f;
  for (int l = threadIdx.x; l < LL; l += 256) {
    int oy = l / WW, ox = l % WW;
    int yy = oy + di - 1, xx = ox + dj - 1;
    float v = (yy >= 0 && yy < HH && xx >= 0 && xx < WW) ? xr[yy * WW + xx] : 0.f;
    mx = fmaxf(mx, fabsf(v));
  }
  float mw = 0.f;
  for (int co = threadIdx.x; co < CO; co += 256) mw = fmaxf(mw, fabsf(wq[co * KK + k]));
  mx = block_max<256>(mx);
  mw = block_max<256>(mw);
  if (threadIdx.x == 0) atomicMax(maxp_bits, __float_as_uint(mx * mw));
}

// ---------- k_fi1: FI1 on all MAC products, fully parallel, store p ----------
// grid (784, 72): thread = one outi, KPT=4 consecutive k's (independent ciphers
// interleaved for ILP). Wave = 64 consecutive outi at fixed k -> same skip
// granularity as before (bit-identical behavior).
__global__ __launch_bounds__(256) void k_fi1(const float* __restrict__ x,
                                             const float* __restrict__ wq,
                                             const unsigned int* __restrict__ scal,
                                             float* __restrict__ pout,
                                             uint32_t ku0, uint32_t ku1,
                                             uint32_t kp0, uint32_t kp1) {
#pragma clang fp contract(off)
  uint32_t outi = blockIdx.x * 256u + threadIdx.x;
  uint32_t k0 = blockIdx.y * KPT;
  float scale_p = __uint_as_float(scal[1]) / 127.0f + 1e-12f;
  uint32_t co = outi / (uint32_t)LL;
  uint32_t l  = outi - co * (uint32_t)LL;
  int oy = (int)(l / WW), ox = (int)(l - (l / WW) * WW);
#pragma unroll
  for (uint32_t kk = 0; kk < KPT; ++kk) {
    uint32_t k = k0 + kk;
    uint32_t ci = k / 9u, r = k - ci * 9u;
    uint32_t d3 = r / 3u;
    int di = (int)d3, dj = (int)(r - d3 * 3u);
    int yy = oy + di - 1, xx = ox + dj - 1;
    bool ok = (yy >= 0) & (yy < HH) & (xx >= 0) & (xx < WW);
    float xv = ok ? x[ci * LL + (uint32_t)yy * WW + (uint32_t)xx] : 0.f;
    float p = xv * wq[co * KK + k];
    uint32_t i0 = outi * (uint32_t)KK + k;
    uint32_t ub = rbits(ku0, ku1, i0);
    pout[k * NOUT + outi] = fi_fwd_skip(p, scale_p, ub, kp0, kp1, i0);
  }
}

// ---------- k_cumsum: in-place serial left-fold p -> c per outi, max|c| ----------
__global__ __launch_bounds__(256) void k_cumsum(float* __restrict__ buf,
                                                unsigned int* __restrict__ maxc_bits) {
#pragma clang fp contract(off)
  uint32_t outi = blockIdx.x * 256u + threadIdx.x;
  float* p = buf + outi;
  float c = 0.f, maxc = 0.f;
  for (int k = 0; k < KK; k += 8) {
    float v[8];
#pragma unroll
    for (int j = 0; j < 8; ++j) v[j] = p[(uint32_t)(k + j) * NOUT];
#pragma unroll
    for (int j = 0; j < 8; ++j) {
      c += v[j];                                  // exact reference fold order
      p[(uint32_t)(k + j) * NOUT] = c;
      maxc = fmaxf(maxc, fabsf(c));
    }
  }
  maxc = block_max<256>(maxc);
  if (threadIdx.x == 0) atomicMax(maxc_bits, __float_as_uint(maxc));
}

// ---------- k_fi2split: FI2 on c, in-block k-split, deterministic merge ----------
// Block = 4 waves; wave kg handles k in [kg*72, kg*72+72) for 64 consecutive outi.
// k=0's cf is unused by the reference (e covers 1..286, ys = k=287) -> skipped.
__global__ __launch_bounds__(256) void k_fi2split(const float* __restrict__ cws,
                                                  const unsigned int* __restrict__ scal,
                                                  unsigned int* __restrict__ maxy_bits,
                                                  float* __restrict__ yout,
                                                  uint32_t ku0, uint32_t ku1,
                                                  uint32_t kp0, uint32_t kp1) {
#pragma clang fp contract(off)
  __shared__ float sE[KG][64];
  __shared__ float sYs[64];
  int tid = threadIdx.x;
  int lane = tid & 63;
  int kg = tid >> 6;                               // 0..3
  uint32_t outi = blockIdx.x * 64u + (uint32_t)lane;   // 3136*64 = NOUT exact
  float scale_c = __uint_as_float(scal[2]) / 127.0f + 1e-12f;
  int ks = (kg == 0) ? 1 : kg * KCH;
  int ke = (kg == KG - 1) ? (KK - 1) : (kg * KCH + KCH);
  const float* cp = cws + (uint32_t)ks * NOUT + outi;
  uint32_t i0 = outi * (uint32_t)KK + (uint32_t)ks;
  float e = 0.f;
#pragma unroll 4
  for (int k = ks; k < ke; ++k) {
    float c = *cp; cp += NOUT;
    uint32_t ub = rbits(ku0, ku1, i0);
    float cf = fi_fwd_skip(c, scale_c, ub, kp0, kp1, i0);
    e += (cf - c);
    ++i0;
  }
  sE[kg][lane] = e;
  if (kg == KG - 1) {                              // k = 287 -> ys
    float c = *cp;
    uint32_t ub = rbits(ku0, ku1, i0);
    float cf = fi_fwd_skip(c, scale_c, ub, kp0, kp1, i0);
    sYs[lane] = cf;
  }
  __syncthreads();
  float maxy = 0.f;
  if (tid < 64) {
    float ee = ((sE[0][lane] + sE[1][lane]) + sE[2][lane]) + sE[3][lane];
    float y = sYs[lane] + ee;
    yout[outi] = y;
    maxy = fabsf(y);
  }
  maxy = block_max<256>(maxy);
  if (tid == 0) atomicMax(maxy_bits, __float_as_uint(maxy));
}

// ---------- fallback (small ws): fused FI1+cumsum, then recompute-FI2 ----------
__global__ __launch_bounds__(64) void k_passC_nostore(const float* __restrict__ x,
                                                      const float* __restrict__ wq,
                                                      const unsigned int* __restrict__ scal,
                                                      unsigned int* __restrict__ maxc_bits,
                                                      uint32_t ku0, uint32_t ku1,
                                                      uint32_t kp0, uint32_t kp1) {
#pragma clang fp contract(off)
  __shared__ float sW[KK];
  int co = blockIdx.y;
  for (int i = threadIdx.x; i < KK; i += 64) sW[i] = wq[co * KK + i];
  __syncthreads();
  int l = blockIdx.x * 64 + threadIdx.x;
  float maxc = 0.f;
  if (l < LL) {
    float scale_p = __uint_as_float(scal[1]) / 127.0f + 1e-12f;
    int oy = l / WW, ox = l % WW;
    uint32_t base = (uint32_t)(co * LL + l) * KK;
    float c = 0.f;
    int k = 0;
    for (int ci = 0; ci < CI; ++ci) {
      const float* xr = x + ci * LL;
#pragma unroll
      for (int di = 0; di < 3; ++di) {
        int yy = oy + di - 1;
        bool yok = (yy >= 0) && (yy < HH);
#pragma unroll
        for (int dj = 0; dj < 3; ++dj, ++k) {
          int xx = ox + dj - 1;
          float xv = (yok && xx >= 0 && xx < WW) ? xr[yy * WW + xx] : 0.f;
          float p = xv * sW[k];
          uint32_t i0 = base + (uint32_t)k;
          uint32_t ub = rbits(ku0, ku1, i0);
          c += fi_fwd_skip(p, scale_p, ub, kp0, kp1, i0);
          maxc = fmaxf(maxc, fabsf(c));
        }
      }
    }
  }
  maxc = block_max<64>(maxc);
  if (threadIdx.x == 0) atomicMax(maxc_bits, __float_as_uint(maxc));
}

__global__ __launch_bounds__(256) void k_passD_rec(const float* __restrict__ x,
                                                   const float* __restrict__ wq,
                                                   const unsigned int* __restrict__ scal,
                                                   unsigned int* __restrict__ maxy_bits,
                                                   float* __restrict__ yout,
                                                   uint32_t ku10, uint32_t ku11,
                                                   uint32_t kp10, uint32_t kp11,
                                                   uint32_t ku20, uint32_t ku21,
                                                   uint32_t kp20, uint32_t kp21) {
#pragma clang fp contract(off)
  __shared__ float sW[KK];
  int co = blockIdx.y;
  for (int i = threadIdx.x; i < KK; i += 256) sW[i] = wq[co * KK + i];
  __syncthreads();
  int l = blockIdx.x * 256 + threadIdx.x;
  float maxy = 0.f;
  if (l < LL) {
    float scale_p = __uint_as_float(scal[1]) / 127.0f + 1e-12f;
    float scale_c = __uint_as_float(scal[2]) / 127.0f + 1e-12f;
    int oy = l / WW, ox = l % WW;
    uint32_t base = (uint32_t)(co * LL + l) * KK;
    float c = 0.f, e = 0.f, ys = 0.f;
    int k = 0;
    for (int ci = 0; ci < CI; ++ci) {
      const float* xr = x + ci * LL;
#pragma unroll
      for (int di = 0; di < 3; ++di) {
        int yy = oy + di - 1;
        bool yok = (yy >= 0) && (yy < HH);
#pragma unroll
        for (int dj = 0; dj < 3; ++dj, ++k) {
          int xx = ox + dj - 1;
          float xv = (yok && xx >= 0 && xx < WW) ? xr[yy * WW + xx] : 0.f;
          float p = xv * sW[k];
          uint32_t i0 = base + (uint32_t)k;
          uint32_t ub1 = rbits(ku10, ku11, i0);
          c += fi_fwd_skip(p, scale_p, ub1, kp10, kp11, i0);
          uint32_t ub2 = rbits(ku20, ku21, i0);
          float cf = fi_fwd_skip(c, scale_c, ub2, kp20, kp21, i0);
          if (k >= 1 && k <= 286) e += (cf - c);
          if (k == 287)           ys = cf;
        }
      }
    }
    float y = ys + e;
    yout[co * LL + l] = y;
    maxy = fabsf(y);
  }
  maxy = block_max<256>(maxy);
  if (threadIdx.x == 0) atomicMax(maxy_bits, __float_as_uint(maxy));
}

// ---------- pass E: FI3 on y, in place in d_out ----------
__global__ __launch_bounds__(256) void k_passE(float* __restrict__ y,
                                               const unsigned int* __restrict__ scal,
                                               uint32_t ku0, uint32_t ku1,
                                               uint32_t kp0, uint32_t kp1) {
#pragma clang fp contract(off)
  uint32_t i = blockIdx.x * 256u + threadIdx.x;
  float scale_y = __uint_as_float(scal[3]) / 127.0f + 1e-12f;
  uint32_t ub = rbits(ku0, ku1, i);
  y[i] = fi_fwd_skip(y[i], scale_y, ub, kp0, kp1, i);
}

extern "C" void kernel_launch(void* const* d_in, const int* in_sizes, int n_in,
                              void* d_out, int out_size, void* d_ws, size_t ws_size,
                              hipStream_t stream) {
  const float* x = (const float*)d_in[0];   // (1,32,56,56)
  const float* w = (const float*)d_in[1];   // (64,32,3,3)
  float* out = (float*)d_out;               // (1,64,56,56)

  unsigned int* scal = (unsigned int*)d_ws; // [1]=max|p| [2]=max|c| [3]=max|y|
  float* wq = (float*)d_ws + 16;            // 18432 floats
  float* cws = (float*)d_ws + CWS_OFF_FLOATS;
  bool bigws = ws_size >= WS_NEED;          // constant across calls -> graph-safe

  // ---- exact JAX key derivation, partitionable threefry ----
  uint32_t K1[2], K2[2], K3[2];
  tf2x32(0u, 42u, 0u, 0u, K1[0], K1[1]);    // split(key(42), 3)
  tf2x32(0u, 42u, 0u, 1u, K2[0], K2[1]);
  tf2x32(0u, 42u, 0u, 2u, K3[0], K3[1]);
  auto derive = [](const uint32_t kk[2], uint32_t U[2], uint32_t P[2]) {
    uint32_t kA0, kA1, kB0, kB1, t0, t1;
    tf2x32(kk[0], kk[1], 0u, 0u, kA0, kA1); // split(key,2)[0] -> uniform key
    tf2x32(kk[0], kk[1], 0u, 1u, kB0, kB1); // split(key,2)[1] -> randint key
    U[0] = kA0; U[1] = kA1;
    tf2x32(kB0, kB1, 0u, 1u, t0, t1);       // randint lower-bits key
    P[0] = t0; P[1] = t1;
  };
  uint32_t U1[2],P1[2],U2[2],P2[2],U3[2],P3[2];
  derive(K1, U1, P1); derive(K2, U2, P2); derive(K3, U3, P3);

  hipMemsetAsync(d_ws, 0, 64, stream);      // zero the atomic-max slots

  k_prep<<<1, 256, 0, stream>>>(w, wq);
  k_maxp<<<KK, 256, 0, stream>>>(x, wq, scal + 1);
  if (bigws) {
    dim3 g1(NOUT / 256, KK / KPT);          // (784, 72)
    k_fi1<<<g1, 256, 0, stream>>>(x, wq, scal, cws,
                                  U1[0], U1[1], P1[0], P1[1]);
    k_cumsum<<<NOUT / 256, 256, 0, stream>>>(cws, scal + 2);
    k_fi2split<<<3136, 256, 0, stream>>>(cws, scal, scal + 3, out,
                                         U2[0], U2[1], P2[0], P2[1]);
  } else {
    dim3 gC(49, 64);
    k_passC_nostore<<<gC, 64, 0, stream>>>(x, wq, scal, scal + 2,
                                           U1[0], U1[1], P1[0], P1[1]);
    dim3 gR(13, 64);
    k_passD_rec<<<gR, 256, 0, stream>>>(x, wq, scal, scal + 3, out,
                                        U1[0], U1[1], P1[0], P1[1],
                                        U2[0], U2[1], P2[0], P2[1]);
  }
  k_passE<<<NOUT / 256, 256, 0, stream>>>(out, scal,
                                          U3[0], U3[1], P3[0], P3[1]);
}

// Round 6
// 572.288 us; speedup vs baseline: 1.7039x; 1.0015x over previous
//
#include <hip/hip_runtime.h>
#include <cstdint>

#define CO   64
#define CI   32
#define HH   56
#define WW   56
#define LL   3136        // 56*56
#define KK   288         // 32*9
#define NOUT 200704u     // 64*3136
#define KG   4           // k-groups per output element in fi2
#define KCH  72          // 288 / KG
#define KPT  4           // k's per block-row in fi1

// flip threshold: u < 0.008f  <=>  (ub>>9) <= 67108  <=>  ub < 67109*512
#define FLIP_LT 34359808u

// workspace layout: [0..63] atomic-max slots | 64.. wq (73728 B) | 81920.. c_ws
// c_ws is used in place: k_fi1 writes p, k_cumsum transforms p -> c in situ.
#define CWS_OFF_FLOATS 20480u                 // 81920 / 4
#define WS_NEED (81920ull + 4ull * 288ull * 200704ull)

__host__ __device__ inline uint32_t rotl32(uint32_t v, uint32_t r) {
#ifdef __HIP_DEVICE_COMPILE__
  return __builtin_amdgcn_alignbit(v, v, 32u - r);   // (v:v)>>(32-r) = rotl(v,r)
#else
  return (v << r) | (v >> (32u - r));
#endif
}

// ---------- threefry2x32 cipher, exact JAX rotation/key schedule ----------
__host__ __device__ inline void tf2x32(uint32_t k0, uint32_t k1,
                                       uint32_t x0, uint32_t x1,
                                       uint32_t& o0, uint32_t& o1) {
  uint32_t ks2 = k0 ^ k1 ^ 0x1BD11BDAu;
  uint32_t v0 = x0 + k0, v1 = x1 + k1;
#define TF_R(r) { v0 += v1; v1 = rotl32(v1, r); v1 ^= v0; }
  TF_R(13) TF_R(15) TF_R(26) TF_R(6)
  v0 += k1;  v1 += ks2 + 1u;
  TF_R(17) TF_R(29) TF_R(16) TF_R(24)
  v0 += ks2; v1 += k0 + 2u;
  TF_R(13) TF_R(15) TF_R(26) TF_R(6)
  v0 += k0;  v1 += k1 + 3u;
  TF_R(17) TF_R(29) TF_R(16) TF_R(24)
  v0 += k1;  v1 += ks2 + 4u;
  TF_R(13) TF_R(15) TF_R(26) TF_R(6)
  v0 += ks2; v1 += k0 + 5u;
#undef TF_R
  o0 = v0; o1 = v1;
}

// partitionable-threefry random bits for flat index i (hi word of iota = 0)
__device__ inline uint32_t rbits(uint32_t k0, uint32_t k1, uint32_t i) {
  uint32_t o0, o1;
  tf2x32(k0, k1, 0u, i, o0, o1);
  return o0 ^ o1;
}

// FI forward with wave-level pos-cipher skip. Bit-identical to the reference:
// integer flip test proven equal to the f32 compare; mask==0 int round-trip
// is the identity, so the skip path y = q*scale is exact. int8 sext
// (v_bfe_i32) == (qf>=128 ? qf-256 : qf) exactly.
__device__ inline float fi_fwd_skip(float x, float scale,
                                    uint32_t ub, uint32_t kp0, uint32_t kp1,
                                    uint32_t i0) {
#pragma clang fp contract(off)
  float q = rintf(x / scale);                    // round-half-even, IEEE div
  q = fminf(127.0f, fmaxf(-128.0f, q));
  bool flip = ub < FLIP_LT;
  float y;
  if (__any(flip)) {                             // wave-uniform branch
    uint32_t pb = rbits(kp0, kp1, i0);
    uint32_t qt = ((uint32_t)(int)q) & 0xFFu;
    uint32_t mask = flip ? (1u << (pb & 7u)) : 0u;
    uint32_t qf = qt ^ mask;
    float qs = (float)(int)(signed char)(qf);    // sext8: == qf>=128?qf-256:qf
    y = qs * scale;
  } else {
    y = q * scale;
  }
  return x + (y - x);                            // x + stop_grad(y - x)
}

template <int BS>
__device__ inline float block_max(float v) {
  __shared__ float s[BS];
  int t = threadIdx.x;
  __syncthreads();
  s[t] = v; __syncthreads();
  for (int o = BS / 2; o > 0; o >>= 1) {
    if (t < o) s[t] = fmaxf(s[t], s[t + o]);
    __syncthreads();
  }
  return s[0];
}

// ---------- kernel 1: quantize weights (_quant_ste forward) ----------
__global__ __launch_bounds__(256) void k_prep(const float* __restrict__ w,
                                              float* __restrict__ wq) {
#pragma clang fp contract(off)
  float m = 0.f;
  for (int i = threadIdx.x; i < CO * KK; i += 256) m = fmaxf(m, fabsf(w[i]));
  m = block_max<256>(m);
  float scale = m / 127.0f + 1e-12f;
  for (int i = threadIdx.x; i < CO * KK; i += 256) {
    float xv = w[i];
    float q = fminf(127.0f, fmaxf(-128.0f, rintf(xv / scale)));
    float y = q * scale;
    wq[i] = xv + (y - xv);
  }
}

// ---------- kernel 2: max|p| = max_k (max_l|xc[l,k]| * max_co|wq[co,k]|) ----------
__global__ __launch_bounds__(256) void k_maxp(const float* __restrict__ x,
                                              const float* __restrict__ wq,
                                              unsigned int* __restrict__ maxp_bits) {
#pragma clang fp contract(off)
  int k = blockIdx.x;                       // 0..287
  int ci = k / 9, r = k % 9, di = r / 3, dj = r % 3;
  const float* xr = x + ci * LL;
  float mx = 0.f;
  for (int l = threadIdx.x; l < LL; l += 256) {
    int oy = l / WW, ox = l % WW;
    int yy = oy + di - 1, xx = ox + dj - 1;
    float v = (yy >= 0 && yy < HH && xx >= 0 && xx < WW) ? xr[yy * WW + xx] : 0.f;
    mx = fmaxf(mx, fabsf(v));
  }
  float mw = 0.f;
  for (int co = threadIdx.x; co < CO; co += 256) mw = fmaxf(mw, fabsf(wq[co * KK + k]));
  mx = block_max<256>(mx);
  mw = block_max<256>(mw);
  if (threadIdx.x == 0) atomicMax(maxp_bits, __float_as_uint(mx * mw));
}

// ---------- k_fi1: FI1 on all MAC products, fully parallel, store p ----------
// grid (13, 72, 64): co = blockIdx.z and k = 4*blockIdx.y + kk are BLOCK-
// uniform -> wq loads and k->(ci,di,dj) decomposition scalarize to SGPRs.
// Wave = 64 consecutive l at fixed k (skip granularity; values unaffected).
__global__ __launch_bounds__(256) void k_fi1(const float* __restrict__ x,
                                             const float* __restrict__ wq,
                                             const unsigned int* __restrict__ scal,
                                             float* __restrict__ pout,
                                             uint32_t ku0, uint32_t ku1,
                                             uint32_t kp0, uint32_t kp1) {
#pragma clang fp contract(off)
  int co = (int)blockIdx.z;
  uint32_t k0 = blockIdx.y * KPT;
  int l = (int)(blockIdx.x * 256u + threadIdx.x);
  if (l >= LL) return;                      // tail waves fully inactive
  float scale_p = __uint_as_float(scal[1]) / 127.0f + 1e-12f;
  int oy = l / WW, ox = l % WW;
  uint32_t outi = (uint32_t)(co * LL + l);
  uint32_t ibase = outi * (uint32_t)KK;
#pragma unroll
  for (uint32_t kk = 0; kk < KPT; ++kk) {
    uint32_t k = k0 + kk;                   // block-uniform
    uint32_t ci = k / 9u, r = k - ci * 9u;
    uint32_t d3 = r / 3u;
    int di = (int)d3 - 1, dj = (int)(r - d3 * 3u) - 1;
    int yy = oy + di, xx = ox + dj;
    bool ok = ((unsigned)yy < (unsigned)HH) & ((unsigned)xx < (unsigned)WW);
    float xv = ok ? x[ci * LL + (uint32_t)yy * WW + (uint32_t)xx] : 0.f;
    float p = xv * wq[(uint32_t)co * KK + k];
    uint32_t i0 = ibase + k;
    uint32_t ub = rbits(ku0, ku1, i0);
    pout[k * NOUT + outi] = fi_fwd_skip(p, scale_p, ub, kp0, kp1, i0);
  }
}

// ---------- k_cumsum: in-place serial left-fold p -> c per outi, max|c| ----------
// Manual register prefetch: batch k+8 loads are issued BEFORE batch k stores
// (source order pins them -- compiler cannot reorder through the alias), so
// HBM latency overlaps the fold instead of serializing behind it.
__global__ __launch_bounds__(256) void k_cumsum(float* __restrict__ buf,
                                                unsigned int* __restrict__ maxc_bits) {
#pragma clang fp contract(off)
  uint32_t outi = blockIdx.x * 256u + threadIdx.x;
  float* p = buf + outi;
  float c = 0.f, maxc = 0.f;
  float cur[8], nxt[8];
#pragma unroll
  for (int j = 0; j < 8; ++j) cur[j] = p[(uint32_t)j * NOUT];
  for (int k = 0; k < KK; k += 8) {
    if (k + 8 < KK) {
#pragma unroll
      for (int j = 0; j < 8; ++j) nxt[j] = p[(uint32_t)(k + 8 + j) * NOUT];
    }
#pragma unroll
    for (int j = 0; j < 8; ++j) {
      c += cur[j];                                // exact reference fold order
      p[(uint32_t)(k + j) * NOUT] = c;
      maxc = fmaxf(maxc, fabsf(c));
    }
#pragma unroll
    for (int j = 0; j < 8; ++j) cur[j] = nxt[j];
  }
  maxc = block_max<256>(maxc);
  if (threadIdx.x == 0) atomicMax(maxc_bits, __float_as_uint(maxc));
}

// ---------- k_fi2split: FI2 on c, in-block k-split, deterministic merge ----------
// Block = 4 waves; wave kg handles k in [kg*72, kg*72+72) for 64 consecutive outi.
// k=0's cf is unused by the reference (e covers 1..286, ys = k=287) -> skipped.
__global__ __launch_bounds__(256) void k_fi2split(const float* __restrict__ cws,
                                                  const unsigned int* __restrict__ scal,
                                                  unsigned int* __restrict__ maxy_bits,
                                                  float* __restrict__ yout,
                                                  uint32_t ku0, uint32_t ku1,
                                                  uint32_t kp0, uint32_t kp1) {
#pragma clang fp contract(off)
  __shared__ float sE[KG][64];
  __shared__ float sYs[64];
  int tid = threadIdx.x;
  int lane = tid & 63;
  int kg = tid >> 6;                               // 0..3
  uint32_t outi = blockIdx.x * 64u + (uint32_t)lane;   // 3136*64 = NOUT exact
  float scale_c = __uint_as_float(scal[2]) / 127.0f + 1e-12f;
  int ks = (kg == 0) ? 1 : kg * KCH;
  int ke = (kg == KG - 1) ? (KK - 1) : (kg * KCH + KCH);
  const float* cp = cws + (uint32_t)ks * NOUT + outi;
  uint32_t i0 = outi * (uint32_t)KK + (uint32_t)ks;
  float e = 0.f;
#pragma unroll 4
  for (int k = ks; k < ke; ++k) {
    float c = *cp; cp += NOUT;
    uint32_t ub = rbits(ku0, ku1, i0);
    float cf = fi_fwd_skip(c, scale_c, ub, kp0, kp1, i0);
    e += (cf - c);
    ++i0;
  }
  sE[kg][lane] = e;
  if (kg == KG - 1) {                              // k = 287 -> ys
    float c = *cp;
    uint32_t ub = rbits(ku0, ku1, i0);
    float cf = fi_fwd_skip(c, scale_c, ub, kp0, kp1, i0);
    sYs[lane] = cf;
  }
  __syncthreads();
  float maxy = 0.f;
  if (tid < 64) {
    float ee = ((sE[0][lane] + sE[1][lane]) + sE[2][lane]) + sE[3][lane];
    float y = sYs[lane] + ee;
    yout[outi] = y;
    maxy = fabsf(y);
  }
  maxy = block_max<256>(maxy);
  if (tid == 0) atomicMax(maxy_bits, __float_as_uint(maxy));
}

// ---------- fallback (small ws): fused FI1+cumsum, then recompute-FI2 ----------
__global__ __launch_bounds__(64) void k_passC_nostore(const float* __restrict__ x,
                                                      const float* __restrict__ wq,
                                                      const unsigned int* __restrict__ scal,
                                                      unsigned int* __restrict__ maxc_bits,
                                                      uint32_t ku0, uint32_t ku1,
                                                      uint32_t kp0, uint32_t kp1) {
#pragma clang fp contract(off)
  __shared__ float sW[KK];
  int co = blockIdx.y;
  for (int i = threadIdx.x; i < KK; i += 64) sW[i] = wq[co * KK + i];
  __syncthreads();
  int l = blockIdx.x * 64 + threadIdx.x;
  float maxc = 0.f;
  if (l < LL) {
    float scale_p = __uint_as_float(scal[1]) / 127.0f + 1e-12f;
    int oy = l / WW, ox = l % WW;
    uint32_t base = (uint32_t)(co * LL + l) * KK;
    float c = 0.f;
    int k = 0;
    for (int ci = 0; ci < CI; ++ci) {
      const float* xr = x + ci * LL;
#pragma unroll
      for (int di = 0; di < 3; ++di) {
        int yy = oy + di - 1;
        bool yok = (yy >= 0) && (yy < HH);
#pragma unroll
        for (int dj = 0; dj < 3; ++dj, ++k) {
          int xx = ox + dj - 1;
          float xv = (yok && xx >= 0 && xx < WW) ? xr[yy * WW + xx] : 0.f;
          float p = xv * sW[k];
          uint32_t i0 = base + (uint32_t)k;
          uint32_t ub = rbits(ku0, ku1, i0);
          c += fi_fwd_skip(p, scale_p, ub, kp0, kp1, i0);
          maxc = fmaxf(maxc, fabsf(c));
        }
      }
    }
  }
  maxc = block_max<64>(maxc);
  if (threadIdx.x == 0) atomicMax(maxc_bits, __float_as_uint(maxc));
}

__global__ __launch_bounds__(256) void k_passD_rec(const float* __restrict__ x,
                                                   const float* __restrict__ wq,
                                                   const unsigned int* __restrict__ scal,
                                                   unsigned int* __restrict__ maxy_bits,
                                                   float* __restrict__ yout,
                                                   uint32_t ku10, uint32_t ku11,
                                                   uint32_t kp10, uint32_t kp11,
                                                   uint32_t ku20, uint32_t ku21,
                                                   uint32_t kp20, uint32_t kp21) {
#pragma clang fp contract(off)
  __shared__ float sW[KK];
  int co = blockIdx.y;
  for (int i = threadIdx.x; i < KK; i += 256) sW[i] = wq[co * KK + i];
  __syncthreads();
  int l = blockIdx.x * 256 + threadIdx.x;
  float maxy = 0.f;
  if (l < LL) {
    float scale_p = __uint_as_float(scal[1]) / 127.0f + 1e-12f;
    float scale_c = __uint_as_float(scal[2]) / 127.0f + 1e-12f;
    int oy = l / WW, ox = l % WW;
    uint32_t base = (uint32_t)(co * LL + l) * KK;
    float c = 0.f, e = 0.f, ys = 0.f;
    int k = 0;
    for (int ci = 0; ci < CI; ++ci) {
      const float* xr = x + ci * LL;
#pragma unroll
      for (int di = 0; di < 3; ++di) {
        int yy = oy + di - 1;
        bool yok = (yy >= 0) && (yy < HH);
#pragma unroll
        for (int dj = 0; dj < 3; ++dj, ++k) {
          int xx = ox + dj - 1;
          float xv = (yok && xx >= 0 && xx < WW) ? xr[yy * WW + xx] : 0.f;
          float p = xv * sW[k];
          uint32_t i0 = base + (uint32_t)k;
          uint32_t ub1 = rbits(ku10, ku11, i0);
          c += fi_fwd_skip(p, scale_p, ub1, kp10, kp11, i0);
          uint32_t ub2 = rbits(ku20, ku21, i0);
          float cf = fi_fwd_skip(c, scale_c, ub2, kp20, kp21, i0);
          if (k >= 1 && k <= 286) e += (cf - c);
          if (k == 287)           ys = cf;
        }
      }
    }
    float y = ys + e;
    yout[co * LL + l] = y;
    maxy = fabsf(y);
  }
  maxy = block_max<256>(maxy);
  if (threadIdx.x == 0) atomicMax(maxy_bits, __float_as_uint(maxy));
}

// ---------- pass E: FI3 on y, in place in d_out ----------
__global__ __launch_bounds__(256) void k_passE(float* __restrict__ y,
                                               const unsigned int* __restrict__ scal,
                                               uint32_t ku0, uint32_t ku1,
                                               uint32_t kp0, uint32_t kp1) {
#pragma clang fp contract(off)
  uint32_t i = blockIdx.x * 256u + threadIdx.x;
  float scale_y = __uint_as_float(scal[3]) / 127.0f + 1e-12f;
  uint32_t ub = rbits(ku0, ku1, i);
  y[i] = fi_fwd_skip(y[i], scale_y, ub, kp0, kp1, i);
}

extern "C" void kernel_launch(void* const* d_in, const int* in_sizes, int n_in,
                              void* d_out, int out_size, void* d_ws, size_t ws_size,
                              hipStream_t stream) {
  const float* x = (const float*)d_in[0];   // (1,32,56,56)
  const float* w = (const float*)d_in[1];   // (64,32,3,3)
  float* out = (float*)d_out;               // (1,64,56,56)

  unsigned int* scal = (unsigned int*)d_ws; // [1]=max|p| [2]=max|c| [3]=max|y|
  float* wq = (float*)d_ws + 16;            // 18432 floats
  float* cws = (float*)d_ws + CWS_OFF_FLOATS;
  bool bigws = ws_size >= WS_NEED;          // constant across calls -> graph-safe

  // ---- exact JAX key derivation, partitionable threefry ----
  uint32_t K1[2], K2[2], K3[2];
  tf2x32(0u, 42u, 0u, 0u, K1[0], K1[1]);    // split(key(42), 3)
  tf2x32(0u, 42u, 0u, 1u, K2[0], K2[1]);
  tf2x32(0u, 42u, 0u, 2u, K3[0], K3[1]);
  auto derive = [](const uint32_t kk[2], uint32_t U[2], uint32_t P[2]) {
    uint32_t kA0, kA1, kB0, kB1, t0, t1;
    tf2x32(kk[0], kk[1], 0u, 0u, kA0, kA1); // split(key,2)[0] -> uniform key
    tf2x32(kk[0], kk[1], 0u, 1u, kB0, kB1); // split(key,2)[1] -> randint key
    U[0] = kA0; U[1] = kA1;
    tf2x32(kB0, kB1, 0u, 1u, t0, t1);       // randint lower-bits key
    P[0] = t0; P[1] = t1;
  };
  uint32_t U1[2],P1[2],U2[2],P2[2],U3[2],P3[2];
  derive(K1, U1, P1); derive(K2, U2, P2); derive(K3, U3, P3);

  hipMemsetAsync(d_ws, 0, 64, stream);      // zero the atomic-max slots

  k_prep<<<1, 256, 0, stream>>>(w, wq);
  k_maxp<<<KK, 256, 0, stream>>>(x, wq, scal + 1);
  if (bigws) {
    dim3 g1(13, KK / KPT, CO);              // (13, 72, 64), block-uniform co/k
    k_fi1<<<g1, 256, 0, stream>>>(x, wq, scal, cws,
                                  U1[0], U1[1], P1[0], P1[1]);
    k_cumsum<<<NOUT / 256, 256, 0, stream>>>(cws, scal + 2);
    k_fi2split<<<3136, 256, 0, stream>>>(cws, scal, scal + 3, out,
                                         U2[0], U2[1], P2[0], P2[1]);
  } else {
    dim3 gC(49, 64);
    k_passC_nostore<<<gC, 64, 0, stream>>>(x, wq, scal, scal + 2,
                                           U1[0], U1[1], P1[0], P1[1]);
    dim3 gR(13, 64);
    k_passD_rec<<<gR, 256, 0, stream>>>(x, wq, scal, scal + 3, out,
                                        U1[0], U1[1], P1[0], P1[1],
                                        U2[0], U2[1], P2[0], P2[1]);
  }
  k_passE<<<NOUT / 256, 256, 0, stream>>>(out, scal,
                                          U3[0], U3[1], P3[0], P3[1]);
}

// Round 7
// 504.530 us; speedup vs baseline: 1.9328x; 1.1343x over previous
//
#include <hip/hip_runtime.h>
#include <cstdint>

#define CO   64
#define CI   32
#define HH   56
#define WW   56
#define LL   3136        // 56*56
#define KK   288         // 32*9
#define NOUT 200704u     // 64*3136
#define KG   4           // k-groups per output element in fi2
#define KCH  72          // 288 / KG
#define TO   32          // outi-tile per block in fused fi1+cumsum

// flip threshold: u < 0.008f  <=>  (ub>>9) <= 67108  <=>  ub < 67109*512
#define FLIP_LT 34359808u

// workspace layout: [0..63] atomic-max slots | 64.. wq (73728 B) | 81920.. c_ws
#define CWS_OFF_FLOATS 20480u                 // 81920 / 4
#define WS_NEED (81920ull + 4ull * 288ull * 200704ull)

__host__ __device__ inline uint32_t rotl32(uint32_t v, uint32_t r) {
#ifdef __HIP_DEVICE_COMPILE__
  return __builtin_amdgcn_alignbit(v, v, 32u - r);   // (v:v)>>(32-r) = rotl(v,r)
#else
  return (v << r) | (v >> (32u - r));
#endif
}

// ---------- threefry2x32 cipher, exact JAX rotation/key schedule ----------
__host__ __device__ inline void tf2x32(uint32_t k0, uint32_t k1,
                                       uint32_t x0, uint32_t x1,
                                       uint32_t& o0, uint32_t& o1) {
  uint32_t ks2 = k0 ^ k1 ^ 0x1BD11BDAu;
  uint32_t v0 = x0 + k0, v1 = x1 + k1;
#define TF_R(r) { v0 += v1; v1 = rotl32(v1, r); v1 ^= v0; }
  TF_R(13) TF_R(15) TF_R(26) TF_R(6)
  v0 += k1;  v1 += ks2 + 1u;
  TF_R(17) TF_R(29) TF_R(16) TF_R(24)
  v0 += ks2; v1 += k0 + 2u;
  TF_R(13) TF_R(15) TF_R(26) TF_R(6)
  v0 += k0;  v1 += k1 + 3u;
  TF_R(17) TF_R(29) TF_R(16) TF_R(24)
  v0 += k1;  v1 += ks2 + 4u;
  TF_R(13) TF_R(15) TF_R(26) TF_R(6)
  v0 += ks2; v1 += k0 + 5u;
#undef TF_R
  o0 = v0; o1 = v1;
}

// partitionable-threefry random bits for flat index i (hi word of iota = 0)
__device__ inline uint32_t rbits(uint32_t k0, uint32_t k1, uint32_t i) {
  uint32_t o0, o1;
  tf2x32(k0, k1, 0u, i, o0, o1);
  return o0 ^ o1;
}

// FI forward with wave-level pos-cipher skip. Bit-identical to the reference:
// integer flip test == the f32 uniform compare; mask==0 int round-trip is the
// identity so the skip path y = q*scale is exact; sext8 == qf>=128?qf-256:qf.
__device__ inline float fi_fwd_skip(float x, float scale,
                                    uint32_t ub, uint32_t kp0, uint32_t kp1,
                                    uint32_t i0) {
#pragma clang fp contract(off)
  float q = rintf(x / scale);                    // round-half-even, IEEE div
  q = fminf(127.0f, fmaxf(-128.0f, q));
  bool flip = ub < FLIP_LT;
  float y;
  if (__any(flip)) {                             // wave-uniform branch
    uint32_t pb = rbits(kp0, kp1, i0);
    uint32_t qt = ((uint32_t)(int)q) & 0xFFu;
    uint32_t mask = flip ? (1u << (pb & 7u)) : 0u;
    uint32_t qf = qt ^ mask;
    float qs = (float)(int)(signed char)(qf);
    y = qs * scale;
  } else {
    y = q * scale;
  }
  return x + (y - x);                            // x + stop_grad(y - x)
}

template <int BS>
__device__ inline float block_max(float v) {
  __shared__ float s[BS];
  int t = threadIdx.x;
  __syncthreads();
  s[t] = v; __syncthreads();
  for (int o = BS / 2; o > 0; o >>= 1) {
    if (t < o) s[t] = fmaxf(s[t], s[t + o]);
    __syncthreads();
  }
  return s[0];
}

// ---------- kernel 1: quantize weights (_quant_ste forward) ----------
__global__ __launch_bounds__(256) void k_prep(const float* __restrict__ w,
                                              float* __restrict__ wq) {
#pragma clang fp contract(off)
  float m = 0.f;
  for (int i = threadIdx.x; i < CO * KK; i += 256) m = fmaxf(m, fabsf(w[i]));
  m = block_max<256>(m);
  float scale = m / 127.0f + 1e-12f;
  for (int i = threadIdx.x; i < CO * KK; i += 256) {
    float xv = w[i];
    float q = fminf(127.0f, fmaxf(-128.0f, rintf(xv / scale)));
    float y = q * scale;
    wq[i] = xv + (y - xv);
  }
}

// ---------- kernel 2: max|p| = max_k (max_l|xc[l,k]| * max_co|wq[co,k]|) ----------
__global__ __launch_bounds__(256) void k_maxp(const float* __restrict__ x,
                                              const float* __restrict__ wq,
                                              unsigned int* __restrict__ maxp_bits) {
#pragma clang fp contract(off)
  int k = blockIdx.x;                       // 0..287
  int ci = k / 9, r = k % 9, di = r / 3, dj = r % 3;
  const float* xr = x + ci * LL;
  float mx = 0.f;
  for (int l = threadIdx.x; l < LL; l += 256) {
    int oy = l / WW, ox = l % WW;
    int yy = oy + di - 1, xx = ox + dj - 1;
    float v = (yy >= 0 && yy < HH && xx >= 0 && xx < WW) ? xr[yy * WW + xx] : 0.f;
    mx = fmaxf(mx, fabsf(v));
  }
  float mw = 0.f;
  for (int co = threadIdx.x; co < CO; co += 256) mw = fmaxf(mw, fabsf(wq[co * KK + k]));
  mx = block_max<256>(mx);
  mw = block_max<256>(mw);
  if (threadIdx.x == 0) atomicMax(maxp_bits, __float_as_uint(mx * mw));
}

// ---------- k_fi1cs: fused FI1 + serial cumsum via LDS tile, store c ----------
// Block = 256 threads = 8 k-slices x 32 outi. Phase 1: FI1 into sP[k][o]
// (thread (s,o) covers k in [36s,36s+36) = 4 input channels x 9 taps).
// Phase 2: lanes 0..31 run the exact f32 left-fold per outi in LDS (order
// identical to the reference cumsum). Phase 3: coalesced write-out of c.
// Eliminates the 452 MB p-buffer round-trip of the split version.
__global__ __launch_bounds__(256) void k_fi1cs(const float* __restrict__ x,
                                               const float* __restrict__ wq,
                                               const unsigned int* __restrict__ scal,
                                               unsigned int* __restrict__ maxc_bits,
                                               float* __restrict__ cws,
                                               uint32_t ku0, uint32_t ku1,
                                               uint32_t kp0, uint32_t kp1) {
#pragma clang fp contract(off)
  __shared__ float sW[KK];                  // 1152 B
  __shared__ float sP[KK][TO];              // 36864 B
  int tid = threadIdx.x;
  uint32_t outi0 = blockIdx.x * (uint32_t)TO;
  int co = (int)(outi0 / (uint32_t)LL);     // block-uniform (32 | 3136)
  for (int i = tid; i < KK; i += 256) sW[i] = wq[co * KK + i];
  __syncthreads();

  int o = tid & 31, s = tid >> 5;           // s in 0..7
  uint32_t outi = outi0 + (uint32_t)o;
  int l = (int)(outi - (uint32_t)co * LL);
  int oy = l / WW, ox = l % WW;
  float scale_p = __uint_as_float(scal[1]) / 127.0f + 1e-12f;
  uint32_t ibase = outi * (uint32_t)KK;

  int k = s * 36;                           // 36 = 4 ci * 9 taps
  int ci0 = s * 4;
  for (int c4 = 0; c4 < 4; ++c4) {
    const float* xr = x + (ci0 + c4) * LL;
#pragma unroll
    for (int di = 0; di < 3; ++di) {
      int yy = oy + di - 1;
      bool yok = (yy >= 0) && (yy < HH);
#pragma unroll
      for (int dj = 0; dj < 3; ++dj, ++k) {
        int xx = ox + dj - 1;
        float xv = (yok && xx >= 0 && xx < WW) ? xr[yy * WW + xx] : 0.f;
        float p = xv * sW[k];
        uint32_t i0 = ibase + (uint32_t)k;
        uint32_t ub = rbits(ku0, ku1, i0);
        sP[k][o] = fi_fwd_skip(p, scale_p, ub, kp0, kp1, i0);
      }
    }
  }
  __syncthreads();

  // Phase 2: exact serial left-fold per outi (lanes 0..31), in place in LDS.
  float maxc = 0.f;
  if (tid < TO) {
    float c = 0.f;
#pragma unroll 8
    for (int kk = 0; kk < KK; ++kk) {
      c += sP[kk][tid];                     // exact reference fold order
      sP[kk][tid] = c;
      maxc = fmaxf(maxc, fabsf(c));
    }
  }
  maxc = block_max<256>(maxc);              // also barriers phase 2 -> phase 3
  if (tid == 0) atomicMax(maxc_bits, __float_as_uint(maxc));

  // Phase 3: coalesced write-out of c in the [k][outi] layout fi2 consumes.
  for (int kk = s; kk < KK; kk += 8)
    cws[(uint32_t)kk * NOUT + outi0 + (uint32_t)o] = sP[kk][o];
}

// ---------- k_fi2split: FI2 on c, in-block k-split, deterministic merge ----------
// Block = 4 waves; wave kg handles k in [kg*72, kg*72+72) for 64 consecutive outi.
// k=0's cf is unused by the reference (e covers 1..286, ys = k=287) -> skipped.
__global__ __launch_bounds__(256) void k_fi2split(const float* __restrict__ cws,
                                                  const unsigned int* __restrict__ scal,
                                                  unsigned int* __restrict__ maxy_bits,
                                                  float* __restrict__ yout,
                                                  uint32_t ku0, uint32_t ku1,
                                                  uint32_t kp0, uint32_t kp1) {
#pragma clang fp contract(off)
  __shared__ float sE[KG][64];
  __shared__ float sYs[64];
  int tid = threadIdx.x;
  int lane = tid & 63;
  int kg = tid >> 6;                               // 0..3
  uint32_t outi = blockIdx.x * 64u + (uint32_t)lane;   // 3136*64 = NOUT exact
  float scale_c = __uint_as_float(scal[2]) / 127.0f + 1e-12f;
  int ks = (kg == 0) ? 1 : kg * KCH;
  int ke = (kg == KG - 1) ? (KK - 1) : (kg * KCH + KCH);
  const float* cp = cws + (uint32_t)ks * NOUT + outi;
  uint32_t i0 = outi * (uint32_t)KK + (uint32_t)ks;
  float e = 0.f;
#pragma unroll 4
  for (int k = ks; k < ke; ++k) {
    float c = *cp; cp += NOUT;
    uint32_t ub = rbits(ku0, ku1, i0);
    float cf = fi_fwd_skip(c, scale_c, ub, kp0, kp1, i0);
    e += (cf - c);
    ++i0;
  }
  sE[kg][lane] = e;
  if (kg == KG - 1) {                              // k = 287 -> ys
    float c = *cp;
    uint32_t ub = rbits(ku0, ku1, i0);
    float cf = fi_fwd_skip(c, scale_c, ub, kp0, kp1, i0);
    sYs[lane] = cf;
  }
  __syncthreads();
  float maxy = 0.f;
  if (tid < 64) {
    float ee = ((sE[0][lane] + sE[1][lane]) + sE[2][lane]) + sE[3][lane];
    float y = sYs[lane] + ee;
    yout[outi] = y;
    maxy = fabsf(y);
  }
  maxy = block_max<256>(maxy);
  if (tid == 0) atomicMax(maxy_bits, __float_as_uint(maxy));
}

// ---------- fallback (small ws): fused FI1+cumsum, then recompute-FI2 ----------
__global__ __launch_bounds__(64) void k_passC_nostore(const float* __restrict__ x,
                                                      const float* __restrict__ wq,
                                                      const unsigned int* __restrict__ scal,
                                                      unsigned int* __restrict__ maxc_bits,
                                                      uint32_t ku0, uint32_t ku1,
                                                      uint32_t kp0, uint32_t kp1) {
#pragma clang fp contract(off)
  __shared__ float sW[KK];
  int co = blockIdx.y;
  for (int i = threadIdx.x; i < KK; i += 64) sW[i] = wq[co * KK + i];
  __syncthreads();
  int l = blockIdx.x * 64 + threadIdx.x;
  float maxc = 0.f;
  if (l < LL) {
    float scale_p = __uint_as_float(scal[1]) / 127.0f + 1e-12f;
    int oy = l / WW, ox = l % WW;
    uint32_t base = (uint32_t)(co * LL + l) * KK;
    float c = 0.f;
    int k = 0;
    for (int ci = 0; ci < CI; ++ci) {
      const float* xr = x + ci * LL;
#pragma unroll
      for (int di = 0; di < 3; ++di) {
        int yy = oy + di - 1;
        bool yok = (yy >= 0) && (yy < HH);
#pragma unroll
        for (int dj = 0; dj < 3; ++dj, ++k) {
          int xx = ox + dj - 1;
          float xv = (yok && xx >= 0 && xx < WW) ? xr[yy * WW + xx] : 0.f;
          float p = xv * sW[k];
          uint32_t i0 = base + (uint32_t)k;
          uint32_t ub = rbits(ku0, ku1, i0);
          c += fi_fwd_skip(p, scale_p, ub, kp0, kp1, i0);
          maxc = fmaxf(maxc, fabsf(c));
        }
      }
    }
  }
  maxc = block_max<64>(maxc);
  if (threadIdx.x == 0) atomicMax(maxc_bits, __float_as_uint(maxc));
}

__global__ __launch_bounds__(256) void k_passD_rec(const float* __restrict__ x,
                                                   const float* __restrict__ wq,
                                                   const unsigned int* __restrict__ scal,
                                                   unsigned int* __restrict__ maxy_bits,
                                                   float* __restrict__ yout,
                                                   uint32_t ku10, uint32_t ku11,
                                                   uint32_t kp10, uint32_t kp11,
                                                   uint32_t ku20, uint32_t ku21,
                                                   uint32_t kp20, uint32_t kp21) {
#pragma clang fp contract(off)
  __shared__ float sW[KK];
  int co = blockIdx.y;
  for (int i = threadIdx.x; i < KK; i += 256) sW[i] = wq[co * KK + i];
  __syncthreads();
  int l = blockIdx.x * 256 + threadIdx.x;
  float maxy = 0.f;
  if (l < LL) {
    float scale_p = __uint_as_float(scal[1]) / 127.0f + 1e-12f;
    float scale_c = __uint_as_float(scal[2]) / 127.0f + 1e-12f;
    int oy = l / WW, ox = l % WW;
    uint32_t base = (uint32_t)(co * LL + l) * KK;
    float c = 0.f, e = 0.f, ys = 0.f;
    int k = 0;
    for (int ci = 0; ci < CI; ++ci) {
      const float* xr = x + ci * LL;
#pragma unroll
      for (int di = 0; di < 3; ++di) {
        int yy = oy + di - 1;
        bool yok = (yy >= 0) && (yy < HH);
#pragma unroll
        for (int dj = 0; dj < 3; ++dj, ++k) {
          int xx = ox + dj - 1;
          float xv = (yok && xx >= 0 && xx < WW) ? xr[yy * WW + xx] : 0.f;
          float p = xv * sW[k];
          uint32_t i0 = base + (uint32_t)k;
          uint32_t ub1 = rbits(ku10, ku11, i0);
          c += fi_fwd_skip(p, scale_p, ub1, kp10, kp11, i0);
          uint32_t ub2 = rbits(ku20, ku21, i0);
          float cf = fi_fwd_skip(c, scale_c, ub2, kp20, kp21, i0);
          if (k >= 1 && k <= 286) e += (cf - c);
          if (k == 287)           ys = cf;
        }
      }
    }
    float y = ys + e;
    yout[co * LL + l] = y;
    maxy = fabsf(y);
  }
  maxy = block_max<256>(maxy);
  if (threadIdx.x == 0) atomicMax(maxy_bits, __float_as_uint(maxy));
}

// ---------- pass E: FI3 on y, in place in d_out ----------
__global__ __launch_bounds__(256) void k_passE(float* __restrict__ y,
                                               const unsigned int* __restrict__ scal,
                                               uint32_t ku0, uint32_t ku1,
                                               uint32_t kp0, uint32_t kp1) {
#pragma clang fp contract(off)
  uint32_t i = blockIdx.x * 256u + threadIdx.x;
  float scale_y = __uint_as_float(scal[3]) / 127.0f + 1e-12f;
  uint32_t ub = rbits(ku0, ku1, i);
  y[i] = fi_fwd_skip(y[i], scale_y, ub, kp0, kp1, i);
}

extern "C" void kernel_launch(void* const* d_in, const int* in_sizes, int n_in,
                              void* d_out, int out_size, void* d_ws, size_t ws_size,
                              hipStream_t stream) {
  const float* x = (const float*)d_in[0];   // (1,32,56,56)
  const float* w = (const float*)d_in[1];   // (64,32,3,3)
  float* out = (float*)d_out;               // (1,64,56,56)

  unsigned int* scal = (unsigned int*)d_ws; // [1]=max|p| [2]=max|c| [3]=max|y|
  float* wq = (float*)d_ws + 16;            // 18432 floats
  float* cws = (float*)d_ws + CWS_OFF_FLOATS;
  bool bigws = ws_size >= WS_NEED;          // constant across calls -> graph-safe

  // ---- exact JAX key derivation, partitionable threefry ----
  uint32_t K1[2], K2[2], K3[2];
  tf2x32(0u, 42u, 0u, 0u, K1[0], K1[1]);    // split(key(42), 3)
  tf2x32(0u, 42u, 0u, 1u, K2[0], K2[1]);
  tf2x32(0u, 42u, 0u, 2u, K3[0], K3[1]);
  auto derive = [](const uint32_t kk[2], uint32_t U[2], uint32_t P[2]) {
    uint32_t kA0, kA1, kB0, kB1, t0, t1;
    tf2x32(kk[0], kk[1], 0u, 0u, kA0, kA1); // split(key,2)[0] -> uniform key
    tf2x32(kk[0], kk[1], 0u, 1u, kB0, kB1); // split(key,2)[1] -> randint key
    U[0] = kA0; U[1] = kA1;
    tf2x32(kB0, kB1, 0u, 1u, t0, t1);       // randint lower-bits key
    P[0] = t0; P[1] = t1;
  };
  uint32_t U1[2],P1[2],U2[2],P2[2],U3[2],P3[2];
  derive(K1, U1, P1); derive(K2, U2, P2); derive(K3, U3, P3);

  hipMemsetAsync(d_ws, 0, 64, stream);      // zero the atomic-max slots

  k_prep<<<1, 256, 0, stream>>>(w, wq);
  k_maxp<<<KK, 256, 0, stream>>>(x, wq, scal + 1);
  if (bigws) {
    k_fi1cs<<<NOUT / TO, 256, 0, stream>>>(x, wq, scal, scal + 2, cws,
                                           U1[0], U1[1], P1[0], P1[1]);
    k_fi2split<<<3136, 256, 0, stream>>>(cws, scal, scal + 3, out,
                                         U2[0], U2[1], P2[0], P2[1]);
  } else {
    dim3 gC(49, 64);
    k_passC_nostore<<<gC, 64, 0, stream>>>(x, wq, scal, scal + 2,
                                           U1[0], U1[1], P1[0], P1[1]);
    dim3 gR(13, 64);
    k_passD_rec<<<gR, 256, 0, stream>>>(x, wq, scal, scal + 3, out,
                                        U1[0], U1[1], P1[0], P1[1],
                                        U2[0], U2[1], P2[0], P2[1]);
  }
  k_passE<<<NOUT / 256, 256, 0, stream>>>(out, scal,
                                          U3[0], U3[1], P3[0], P3[1]);
}

// Round 8
// 442.398 us; speedup vs baseline: 2.2042x; 1.1404x over previous
//
#include <hip/hip_runtime.h>
#include <cstdint>

#define CO   64
#define CI   32
#define HH   56
#define WW   56
#define LL   3136        // 56*56
#define KK   288         // 32*9
#define NOUT 200704u     // 64*3136
#define KG   4           // k-groups per output element in fi2
#define KCH  72          // 288 / KG
#define TO   32          // outi-tile per block in fused fi1+cumsum

// flip threshold: u < 0.008f  <=>  (ub>>9) <= 67108  <=>  ub < 67109*512
#define FLIP_LT 34359808u

// workspace layout: [0..63] atomic-max slots | 64.. wq (73728 B) | 81920.. c_ws
#define CWS_OFF_FLOATS 20480u                 // 81920 / 4
#define WS_NEED (81920ull + 4ull * 288ull * 200704ull)

__host__ __device__ inline uint32_t rotl32(uint32_t v, uint32_t r) {
#ifdef __HIP_DEVICE_COMPILE__
  return __builtin_amdgcn_alignbit(v, v, 32u - r);   // (v:v)>>(32-r) = rotl(v,r)
#else
  return (v << r) | (v >> (32u - r));
#endif
}

// ---------- threefry2x32 cipher, exact JAX rotation/key schedule ----------
__host__ __device__ inline void tf2x32(uint32_t k0, uint32_t k1,
                                       uint32_t x0, uint32_t x1,
                                       uint32_t& o0, uint32_t& o1) {
  uint32_t ks2 = k0 ^ k1 ^ 0x1BD11BDAu;
  uint32_t v0 = x0 + k0, v1 = x1 + k1;
#define TF_R(r) { v0 += v1; v1 = rotl32(v1, r); v1 ^= v0; }
  TF_R(13) TF_R(15) TF_R(26) TF_R(6)
  v0 += k1;  v1 += ks2 + 1u;
  TF_R(17) TF_R(29) TF_R(16) TF_R(24)
  v0 += ks2; v1 += k0 + 2u;
  TF_R(13) TF_R(15) TF_R(26) TF_R(6)
  v0 += k0;  v1 += k1 + 3u;
  TF_R(17) TF_R(29) TF_R(16) TF_R(24)
  v0 += k1;  v1 += ks2 + 4u;
  TF_R(13) TF_R(15) TF_R(26) TF_R(6)
  v0 += ks2; v1 += k0 + 5u;
#undef TF_R
  o0 = v0; o1 = v1;
}

// partitionable-threefry random bits for flat index i (hi word of iota = 0)
__device__ inline uint32_t rbits(uint32_t k0, uint32_t k1, uint32_t i) {
  uint32_t o0, o1;
  tf2x32(k0, k1, 0u, i, o0, o1);
  return o0 ^ o1;
}

// FI forward with wave-level pos-cipher skip. Bit-identical to the reference:
// integer flip test == the f32 uniform compare; mask==0 int round-trip is the
// identity so the skip path y = q*scale is exact; sext8 == qf>=128?qf-256:qf.
__device__ inline float fi_fwd_skip(float x, float scale,
                                    uint32_t ub, uint32_t kp0, uint32_t kp1,
                                    uint32_t i0) {
#pragma clang fp contract(off)
  float q = rintf(x / scale);                    // round-half-even, IEEE div
  q = fminf(127.0f, fmaxf(-128.0f, q));
  bool flip = ub < FLIP_LT;
  float y;
  if (__any(flip)) {                             // wave-uniform branch
    uint32_t pb = rbits(kp0, kp1, i0);
    uint32_t qt = ((uint32_t)(int)q) & 0xFFu;
    uint32_t mask = flip ? (1u << (pb & 7u)) : 0u;
    uint32_t qf = qt ^ mask;
    float qs = (float)(int)(signed char)(qf);
    y = qs * scale;
  } else {
    y = q * scale;
  }
  return x + (y - x);                            // x + stop_grad(y - x)
}

template <int BS>
__device__ inline float block_max(float v) {
  __shared__ float s[BS];
  int t = threadIdx.x;
  __syncthreads();
  s[t] = v; __syncthreads();
  for (int o = BS / 2; o > 0; o >>= 1) {
    if (t < o) s[t] = fmaxf(s[t], s[t + o]);
    __syncthreads();
  }
  return s[0];
}

// ---------- kernel 1: quantize weights (_quant_ste forward) ----------
__global__ __launch_bounds__(256) void k_prep(const float* __restrict__ w,
                                              float* __restrict__ wq) {
#pragma clang fp contract(off)
  float m = 0.f;
  for (int i = threadIdx.x; i < CO * KK; i += 256) m = fmaxf(m, fabsf(w[i]));
  m = block_max<256>(m);
  float scale = m / 127.0f + 1e-12f;
  for (int i = threadIdx.x; i < CO * KK; i += 256) {
    float xv = w[i];
    float q = fminf(127.0f, fmaxf(-128.0f, rintf(xv / scale)));
    float y = q * scale;
    wq[i] = xv + (y - xv);
  }
}

// ---------- kernel 2: max|p| = max_k (max_l|xc[l,k]| * max_co|wq[co,k]|) ----------
__global__ __launch_bounds__(256) void k_maxp(const float* __restrict__ x,
                                              const float* __restrict__ wq,
                                              unsigned int* __restrict__ maxp_bits) {
#pragma clang fp contract(off)
  int k = blockIdx.x;                       // 0..287
  int ci = k / 9, r = k % 9, di = r / 3, dj = r % 3;
  const float* xr = x + ci * LL;
  float mx = 0.f;
  for (int l = threadIdx.x; l < LL; l += 256) {
    int oy = l / WW, ox = l % WW;
    int yy = oy + di - 1, xx = ox + dj - 1;
    float v = (yy >= 0 && yy < HH && xx >= 0 && xx < WW) ? xr[yy * WW + xx] : 0.f;
    mx = fmaxf(mx, fabsf(v));
  }
  float mw = 0.f;
  for (int co = threadIdx.x; co < CO; co += 256) mw = fmaxf(mw, fabsf(wq[co * KK + k]));
  mx = block_max<256>(mx);
  mw = block_max<256>(mw);
  if (threadIdx.x == 0) atomicMax(maxp_bits, __float_as_uint(mx * mw));
}

// ---------- k_fi1cs: fused FI1 + serial cumsum via LDS tile, store c ----------
// Block = 256 threads = 8 k-slices x 32 outi. Phase 1 batches each input
// channel's 9 tap-ciphers straight-line (9 independent 20-round chains cover
// the 4-cy VALU dep latency; xv loads issued alongside). Phase 2: lanes 0..31
// run the exact f32 left-fold per outi in LDS. Phase 3: coalesced c write.
__global__ __launch_bounds__(256) void k_fi1cs(const float* __restrict__ x,
                                               const float* __restrict__ wq,
                                               const unsigned int* __restrict__ scal,
                                               unsigned int* __restrict__ maxc_bits,
                                               float* __restrict__ cws,
                                               uint32_t ku0, uint32_t ku1,
                                               uint32_t kp0, uint32_t kp1) {
#pragma clang fp contract(off)
  __shared__ float sW[KK];                  // 1152 B
  __shared__ float sP[KK][TO];              // 36864 B
  int tid = threadIdx.x;
  uint32_t outi0 = blockIdx.x * (uint32_t)TO;
  int co = (int)(outi0 / (uint32_t)LL);     // block-uniform (32 | 3136)
  for (int i = tid; i < KK; i += 256) sW[i] = wq[co * KK + i];
  __syncthreads();

  int o = tid & 31, s = tid >> 5;           // s in 0..7
  uint32_t outi = outi0 + (uint32_t)o;
  int l = (int)(outi - (uint32_t)co * LL);
  int oy = l / WW, ox = l % WW;
  float scale_p = __uint_as_float(scal[1]) / 127.0f + 1e-12f;
  uint32_t ibase = outi * (uint32_t)KK;

  int k = s * 36;                           // 36 = 4 ci * 9 taps
  int ci0 = s * 4;
  for (int c4 = 0; c4 < 4; ++c4) {
    const float* xr = x + (ci0 + c4) * LL;
    float xv[9];
    uint32_t ub[9];
#pragma unroll
    for (int di = 0; di < 3; ++di) {
      int yy = oy + di - 1;
      bool yok = (yy >= 0) && (yy < HH);
#pragma unroll
      for (int dj = 0; dj < 3; ++dj) {
        int xx = ox + dj - 1;
        xv[di * 3 + dj] = (yok && xx >= 0 && xx < WW) ? xr[yy * WW + xx] : 0.f;
      }
    }
#pragma unroll
    for (int j = 0; j < 9; ++j)             // 9 independent cipher chains
      ub[j] = rbits(ku0, ku1, ibase + (uint32_t)(k + j));
#pragma unroll
    for (int j = 0; j < 9; ++j) {
      float p = xv[j] * sW[k + j];
      sP[k + j][o] = fi_fwd_skip(p, scale_p, ub[j], kp0, kp1,
                                 ibase + (uint32_t)(k + j));
    }
    k += 9;
  }
  __syncthreads();

  // Phase 2: exact serial left-fold per outi (lanes 0..31), in place in LDS.
  float maxc = 0.f;
  if (tid < TO) {
    float c = 0.f;
#pragma unroll 8
    for (int kk = 0; kk < KK; ++kk) {
      c += sP[kk][tid];                     // exact reference fold order
      sP[kk][tid] = c;
      maxc = fmaxf(maxc, fabsf(c));
    }
  }
  maxc = block_max<256>(maxc);              // also barriers phase 2 -> phase 3
  if (tid == 0) atomicMax(maxc_bits, __float_as_uint(maxc));

  // Phase 3: coalesced write-out of c in the [k][outi] layout fi2 consumes.
  for (int kk = s; kk < KK; kk += 8)
    cws[(uint32_t)kk * NOUT + outi0 + (uint32_t)o] = sP[kk][o];
}

// ---------- k_fi2split: FI2 on c, in-block k-split, 8-way cipher batching ----
// Block = 4 waves; wave kg handles k in its 72-chunk for 64 consecutive outi.
// Batch of 8: loads issued first (ciphers don't depend on them -> HBM latency
// hides under ~1100 cy of cipher compute), then 8 independent cipher chains,
// then the short fi/e steps in order. Bit-identical to the scalar loop.
__global__ __launch_bounds__(256) void k_fi2split(const float* __restrict__ cws,
                                                  const unsigned int* __restrict__ scal,
                                                  unsigned int* __restrict__ maxy_bits,
                                                  float* __restrict__ yout,
                                                  uint32_t ku0, uint32_t ku1,
                                                  uint32_t kp0, uint32_t kp1) {
#pragma clang fp contract(off)
  __shared__ float sE[KG][64];
  __shared__ float sYs[64];
  int tid = threadIdx.x;
  int lane = tid & 63;
  int kg = tid >> 6;                               // 0..3
  uint32_t outi = blockIdx.x * 64u + (uint32_t)lane;   // 3136*64 = NOUT exact
  float scale_c = __uint_as_float(scal[2]) / 127.0f + 1e-12f;
  int ks = (kg == 0) ? 1 : kg * KCH;
  int ke = (kg == KG - 1) ? (KK - 1) : (kg * KCH + KCH);
  const float* cp = cws + (uint32_t)ks * NOUT + outi;
  uint32_t i0 = outi * (uint32_t)KK + (uint32_t)ks;
  float e = 0.f;
  int k = ks;
  while (k + 8 <= ke) {
    float c8[8];
    uint32_t ub[8];
#pragma unroll
    for (int j = 0; j < 8; ++j) c8[j] = cp[(uint32_t)j * NOUT];  // issue loads
#pragma unroll
    for (int j = 0; j < 8; ++j) ub[j] = rbits(ku0, ku1, i0 + (uint32_t)j);
#pragma unroll
    for (int j = 0; j < 8; ++j) {
      float cf = fi_fwd_skip(c8[j], scale_c, ub[j], kp0, kp1, i0 + (uint32_t)j);
      e += (cf - c8[j]);
    }
    cp += 8u * NOUT; i0 += 8; k += 8;
  }
  for (; k < ke; ++k) {
    float c = *cp; cp += NOUT;
    uint32_t ub = rbits(ku0, ku1, i0);
    float cf = fi_fwd_skip(c, scale_c, ub, kp0, kp1, i0);
    e += (cf - c);
    ++i0;
  }
  sE[kg][lane] = e;
  if (kg == KG - 1) {                              // k = 287 -> ys
    float c = *cp;
    uint32_t ub = rbits(ku0, ku1, i0);
    float cf = fi_fwd_skip(c, scale_c, ub, kp0, kp1, i0);
    sYs[lane] = cf;
  }
  __syncthreads();
  float maxy = 0.f;
  if (tid < 64) {
    float ee = ((sE[0][lane] + sE[1][lane]) + sE[2][lane]) + sE[3][lane];
    float y = sYs[lane] + ee;
    yout[outi] = y;
    maxy = fabsf(y);
  }
  maxy = block_max<256>(maxy);
  if (tid == 0) atomicMax(maxy_bits, __float_as_uint(maxy));
}

// ---------- fallback (small ws): fused FI1+cumsum, then recompute-FI2 ----------
__global__ __launch_bounds__(64) void k_passC_nostore(const float* __restrict__ x,
                                                      const float* __restrict__ wq,
                                                      const unsigned int* __restrict__ scal,
                                                      unsigned int* __restrict__ maxc_bits,
                                                      uint32_t ku0, uint32_t ku1,
                                                      uint32_t kp0, uint32_t kp1) {
#pragma clang fp contract(off)
  __shared__ float sW[KK];
  int co = blockIdx.y;
  for (int i = threadIdx.x; i < KK; i += 64) sW[i] = wq[co * KK + i];
  __syncthreads();
  int l = blockIdx.x * 64 + threadIdx.x;
  float maxc = 0.f;
  if (l < LL) {
    float scale_p = __uint_as_float(scal[1]) / 127.0f + 1e-12f;
    int oy = l / WW, ox = l % WW;
    uint32_t base = (uint32_t)(co * LL + l) * KK;
    float c = 0.f;
    int k = 0;
    for (int ci = 0; ci < CI; ++ci) {
      const float* xr = x + ci * LL;
#pragma unroll
      for (int di = 0; di < 3; ++di) {
        int yy = oy + di - 1;
        bool yok = (yy >= 0) && (yy < HH);
#pragma unroll
        for (int dj = 0; dj < 3; ++dj, ++k) {
          int xx = ox + dj - 1;
          float xv = (yok && xx >= 0 && xx < WW) ? xr[yy * WW + xx] : 0.f;
          float p = xv * sW[k];
          uint32_t i0 = base + (uint32_t)k;
          uint32_t ub = rbits(ku0, ku1, i0);
          c += fi_fwd_skip(p, scale_p, ub, kp0, kp1, i0);
          maxc = fmaxf(maxc, fabsf(c));
        }
      }
    }
  }
  maxc = block_max<64>(maxc);
  if (threadIdx.x == 0) atomicMax(maxc_bits, __float_as_uint(maxc));
}

__global__ __launch_bounds__(256) void k_passD_rec(const float* __restrict__ x,
                                                   const float* __restrict__ wq,
                                                   const unsigned int* __restrict__ scal,
                                                   unsigned int* __restrict__ maxy_bits,
                                                   float* __restrict__ yout,
                                                   uint32_t ku10, uint32_t ku11,
                                                   uint32_t kp10, uint32_t kp11,
                                                   uint32_t ku20, uint32_t ku21,
                                                   uint32_t kp20, uint32_t kp21) {
#pragma clang fp contract(off)
  __shared__ float sW[KK];
  int co = blockIdx.y;
  for (int i = threadIdx.x; i < KK; i += 256) sW[i] = wq[co * KK + i];
  __syncthreads();
  int l = blockIdx.x * 256 + threadIdx.x;
  float maxy = 0.f;
  if (l < LL) {
    float scale_p = __uint_as_float(scal[1]) / 127.0f + 1e-12f;
    float scale_c = __uint_as_float(scal[2]) / 127.0f + 1e-12f;
    int oy = l / WW, ox = l % WW;
    uint32_t base = (uint32_t)(co * LL + l) * KK;
    float c = 0.f, e = 0.f, ys = 0.f;
    int k = 0;
    for (int ci = 0; ci < CI; ++ci) {
      const float* xr = x + ci * LL;
#pragma unroll
      for (int di = 0; di < 3; ++di) {
        int yy = oy + di - 1;
        bool yok = (yy >= 0) && (yy < HH);
#pragma unroll
        for (int dj = 0; dj < 3; ++dj, ++k) {
          int xx = ox + dj - 1;
          float xv = (yok && xx >= 0 && xx < WW) ? xr[yy * WW + xx] : 0.f;
          float p = xv * sW[k];
          uint32_t i0 = base + (uint32_t)k;
          uint32_t ub1 = rbits(ku10, ku11, i0);
          c += fi_fwd_skip(p, scale_p, ub1, kp10, kp11, i0);
          uint32_t ub2 = rbits(ku20, ku21, i0);
          float cf = fi_fwd_skip(c, scale_c, ub2, kp20, kp21, i0);
          if (k >= 1 && k <= 286) e += (cf - c);
          if (k == 287)           ys = cf;
        }
      }
    }
    float y = ys + e;
    yout[co * LL + l] = y;
    maxy = fabsf(y);
  }
  maxy = block_max<256>(maxy);
  if (threadIdx.x == 0) atomicMax(maxy_bits, __float_as_uint(maxy));
}

// ---------- pass E: FI3 on y, in place in d_out ----------
__global__ __launch_bounds__(256) void k_passE(float* __restrict__ y,
                                               const unsigned int* __restrict__ scal,
                                               uint32_t ku0, uint32_t ku1,
                                               uint32_t kp0, uint32_t kp1) {
#pragma clang fp contract(off)
  uint32_t i = blockIdx.x * 256u + threadIdx.x;
  float scale_y = __uint_as_float(scal[3]) / 127.0f + 1e-12f;
  uint32_t ub = rbits(ku0, ku1, i);
  y[i] = fi_fwd_skip(y[i], scale_y, ub, kp0, kp1, i);
}

extern "C" void kernel_launch(void* const* d_in, const int* in_sizes, int n_in,
                              void* d_out, int out_size, void* d_ws, size_t ws_size,
                              hipStream_t stream) {
  const float* x = (const float*)d_in[0];   // (1,32,56,56)
  const float* w = (const float*)d_in[1];   // (64,32,3,3)
  float* out = (float*)d_out;               // (1,64,56,56)

  unsigned int* scal = (unsigned int*)d_ws; // [1]=max|p| [2]=max|c| [3]=max|y|
  float* wq = (float*)d_ws + 16;            // 18432 floats
  float* cws = (float*)d_ws + CWS_OFF_FLOATS;
  bool bigws = ws_size >= WS_NEED;          // constant across calls -> graph-safe

  // ---- exact JAX key derivation, partitionable threefry ----
  uint32_t K1[2], K2[2], K3[2];
  tf2x32(0u, 42u, 0u, 0u, K1[0], K1[1]);    // split(key(42), 3)
  tf2x32(0u, 42u, 0u, 1u, K2[0], K2[1]);
  tf2x32(0u, 42u, 0u, 2u, K3[0], K3[1]);
  auto derive = [](const uint32_t kk[2], uint32_t U[2], uint32_t P[2]) {
    uint32_t kA0, kA1, kB0, kB1, t0, t1;
    tf2x32(kk[0], kk[1], 0u, 0u, kA0, kA1); // split(key,2)[0] -> uniform key
    tf2x32(kk[0], kk[1], 0u, 1u, kB0, kB1); // split(key,2)[1] -> randint key
    U[0] = kA0; U[1] = kA1;
    tf2x32(kB0, kB1, 0u, 1u, t0, t1);       // randint lower-bits key
    P[0] = t0; P[1] = t1;
  };
  uint32_t U1[2],P1[2],U2[2],P2[2],U3[2],P3[2];
  derive(K1, U1, P1); derive(K2, U2, P2); derive(K3, U3, P3);

  hipMemsetAsync(d_ws, 0, 64, stream);      // zero the atomic-max slots

  k_prep<<<1, 256, 0, stream>>>(w, wq);
  k_maxp<<<KK, 256, 0, stream>>>(x, wq, scal + 1);
  if (bigws) {
    k_fi1cs<<<NOUT / TO, 256, 0, stream>>>(x, wq, scal, scal + 2, cws,
                                           U1[0], U1[1], P1[0], P1[1]);
    k_fi2split<<<3136, 256, 0, stream>>>(cws, scal, scal + 3, out,
                                         U2[0], U2[1], P2[0], P2[1]);
  } else {
    dim3 gC(49, 64);
    k_passC_nostore<<<gC, 64, 0, stream>>>(x, wq, scal, scal + 2,
                                           U1[0], U1[1], P1[0], P1[1]);
    dim3 gR(13, 64);
    k_passD_rec<<<gR, 256, 0, stream>>>(x, wq, scal, scal + 3, out,
                                        U1[0], U1[1], P1[0], P1[1],
                                        U2[0], U2[1], P2[0], P2[1]);
  }
  k_passE<<<NOUT / 256, 256, 0, stream>>>(out, scal,
                                          U3[0], U3[1], P3[0], P3[1]);
}

// Round 9
// 439.468 us; speedup vs baseline: 2.2189x; 1.0067x over previous
//
#include <hip/hip_runtime.h>
#include <cstdint>

#define CO   64
#define CI   32
#define HH   56
#define WW   56
#define LL   3136        // 56*56
#define KK   288         // 32*9
#define KH   144         // KK/2 — double-pumped LDS tile
#define NOUT 200704u     // 64*3136
#define KG   4           // k-groups per output element in fi2
#define KCH  72          // 288 / KG
#define TO   32          // outi-tile per block in fused fi1+cumsum

// flip threshold: u < 0.008f  <=>  (ub>>9) <= 67108  <=>  ub < 67109*512
#define FLIP_LT 34359808u

// workspace layout: [0..63] atomic-max slots | 64.. wq (73728 B) | 81920.. c_ws
#define CWS_OFF_FLOATS 20480u                 // 81920 / 4
#define WS_NEED (81920ull + 4ull * 288ull * 200704ull)

__host__ __device__ inline uint32_t rotl32(uint32_t v, uint32_t r) {
#ifdef __HIP_DEVICE_COMPILE__
  return __builtin_amdgcn_alignbit(v, v, 32u - r);   // (v:v)>>(32-r) = rotl(v,r)
#else
  return (v << r) | (v >> (32u - r));
#endif
}

// ---------- threefry2x32 cipher, exact JAX rotation/key schedule ----------
__host__ __device__ inline void tf2x32(uint32_t k0, uint32_t k1,
                                       uint32_t x0, uint32_t x1,
                                       uint32_t& o0, uint32_t& o1) {
  uint32_t ks2 = k0 ^ k1 ^ 0x1BD11BDAu;
  uint32_t v0 = x0 + k0, v1 = x1 + k1;
#define TF_R(r) { v0 += v1; v1 = rotl32(v1, r); v1 ^= v0; }
  TF_R(13) TF_R(15) TF_R(26) TF_R(6)
  v0 += k1;  v1 += ks2 + 1u;
  TF_R(17) TF_R(29) TF_R(16) TF_R(24)
  v0 += ks2; v1 += k0 + 2u;
  TF_R(13) TF_R(15) TF_R(26) TF_R(6)
  v0 += k0;  v1 += k1 + 3u;
  TF_R(17) TF_R(29) TF_R(16) TF_R(24)
  v0 += k1;  v1 += ks2 + 4u;
  TF_R(13) TF_R(15) TF_R(26) TF_R(6)
  v0 += ks2; v1 += k0 + 5u;
#undef TF_R
  o0 = v0; o1 = v1;
}

// partitionable-threefry random bits for flat index i (hi word of iota = 0)
__device__ inline uint32_t rbits(uint32_t k0, uint32_t k1, uint32_t i) {
  uint32_t o0, o1;
  tf2x32(k0, k1, 0u, i, o0, o1);
  return o0 ^ o1;
}

// FI forward with wave-level pos-cipher skip. Bit-identical to the reference:
// integer flip test == the f32 uniform compare; mask==0 int round-trip is the
// identity so the skip path y = q*scale is exact; sext8 == qf>=128?qf-256:qf.
__device__ inline float fi_fwd_skip(float x, float scale,
                                    uint32_t ub, uint32_t kp0, uint32_t kp1,
                                    uint32_t i0) {
#pragma clang fp contract(off)
  float q = rintf(x / scale);                    // round-half-even, IEEE div
  q = fminf(127.0f, fmaxf(-128.0f, q));
  bool flip = ub < FLIP_LT;
  float y;
  if (__any(flip)) {                             // wave-uniform branch
    uint32_t pb = rbits(kp0, kp1, i0);
    uint32_t qt = ((uint32_t)(int)q) & 0xFFu;
    uint32_t mask = flip ? (1u << (pb & 7u)) : 0u;
    uint32_t qf = qt ^ mask;
    float qs = (float)(int)(signed char)(qf);
    y = qs * scale;
  } else {
    y = q * scale;
  }
  return x + (y - x);                            // x + stop_grad(y - x)
}

template <int BS>
__device__ inline float block_max(float v) {
  __shared__ float s[BS];
  int t = threadIdx.x;
  __syncthreads();
  s[t] = v; __syncthreads();
  for (int o = BS / 2; o > 0; o >>= 1) {
    if (t < o) s[t] = fmaxf(s[t], s[t + o]);
    __syncthreads();
  }
  return s[0];
}

// ---------- kernel 1: quantize weights (_quant_ste forward) ----------
__global__ __launch_bounds__(256) void k_prep(const float* __restrict__ w,
                                              float* __restrict__ wq) {
#pragma clang fp contract(off)
  float m = 0.f;
  for (int i = threadIdx.x; i < CO * KK; i += 256) m = fmaxf(m, fabsf(w[i]));
  m = block_max<256>(m);
  float scale = m / 127.0f + 1e-12f;
  for (int i = threadIdx.x; i < CO * KK; i += 256) {
    float xv = w[i];
    float q = fminf(127.0f, fmaxf(-128.0f, rintf(xv / scale)));
    float y = q * scale;
    wq[i] = xv + (y - xv);
  }
}

// ---------- kernel 2: max|p| = max_k (max_l|xc[l,k]| * max_co|wq[co,k]|) ----------
__global__ __launch_bounds__(256) void k_maxp(const float* __restrict__ x,
                                              const float* __restrict__ wq,
                                              unsigned int* __restrict__ maxp_bits) {
#pragma clang fp contract(off)
  int k = blockIdx.x;                       // 0..287
  int ci = k / 9, r = k % 9, di = r / 3, dj = r % 3;
  const float* xr = x + ci * LL;
  float mx = 0.f;
  for (int l = threadIdx.x; l < LL; l += 256) {
    int oy = l / WW, ox = l % WW;
    int yy = oy + di - 1, xx = ox + dj - 1;
    float v = (yy >= 0 && yy < HH && xx >= 0 && xx < WW) ? xr[yy * WW + xx] : 0.f;
    mx = fmaxf(mx, fabsf(v));
  }
  float mw = 0.f;
  for (int co = threadIdx.x; co < CO; co += 256) mw = fmaxf(mw, fabsf(wq[co * KK + k]));
  mx = block_max<256>(mx);
  mw = block_max<256>(mw);
  if (threadIdx.x == 0) atomicMax(maxp_bits, __float_as_uint(mx * mw));
}

// ---------- k_fi1cs: fused FI1 + serial cumsum, double-pumped LDS tile ----------
// LDS = sW(1152B) + sP[144][32](18432B) = 19.6KB -> 8 blocks/CU = 32 waves/CU
// (vs 4 blocks at the full 288-row tile). The 288-fold runs as two 144-folds
// with the carry in a register across halves — identical adds, identical order.
// maxc reduced via wave-0 shuffle (phase-2 owners are lanes 0..31) + 1 atomic.
__global__ __launch_bounds__(256) void k_fi1cs(const float* __restrict__ x,
                                               const float* __restrict__ wq,
                                               const unsigned int* __restrict__ scal,
                                               unsigned int* __restrict__ maxc_bits,
                                               float* __restrict__ cws,
                                               uint32_t ku0, uint32_t ku1,
                                               uint32_t kp0, uint32_t kp1) {
#pragma clang fp contract(off)
  __shared__ float sW[KK];                  // 1152 B
  __shared__ float sP[KH][TO];              // 18432 B
  int tid = threadIdx.x;
  uint32_t outi0 = blockIdx.x * (uint32_t)TO;
  int co = (int)(outi0 / (uint32_t)LL);     // block-uniform (32 | 3136)
  for (int i = tid; i < KK; i += 256) sW[i] = wq[co * KK + i];
  __syncthreads();

  int o = tid & 31, s = tid >> 5;           // s in 0..7
  uint32_t outi = outi0 + (uint32_t)o;
  int l = (int)(outi - (uint32_t)co * LL);
  int oy = l / WW, ox = l % WW;
  float scale_p = __uint_as_float(scal[1]) / 127.0f + 1e-12f;
  uint32_t ibase = outi * (uint32_t)KK;

  float carry = 0.f, maxc = 0.f;
  for (int half = 0; half < 2; ++half) {
    int kbase = half * KH;
    // Phase 1: slice s covers k in [kbase+18s, kbase+18s+18) = 2 channels x 9.
    int k = kbase + s * 18;
    int ci0 = k / 9;                        // = 16*half + 2*s
    for (int c2 = 0; c2 < 2; ++c2) {
      const float* xr = x + (ci0 + c2) * LL;
      float xv[9];
      uint32_t ub[9];
#pragma unroll
      for (int di = 0; di < 3; ++di) {
        int yy = oy + di - 1;
        bool yok = (yy >= 0) && (yy < HH);
#pragma unroll
        for (int dj = 0; dj < 3; ++dj) {
          int xx = ox + dj - 1;
          xv[di * 3 + dj] = (yok && xx >= 0 && xx < WW) ? xr[yy * WW + xx] : 0.f;
        }
      }
#pragma unroll
      for (int j = 0; j < 9; ++j)           // 9 independent cipher chains
        ub[j] = rbits(ku0, ku1, ibase + (uint32_t)(k + j));
#pragma unroll
      for (int j = 0; j < 9; ++j) {
        float p = xv[j] * sW[k + j];
        sP[k + j - kbase][o] = fi_fwd_skip(p, scale_p, ub[j], kp0, kp1,
                                           ibase + (uint32_t)(k + j));
      }
      k += 9;
    }
    __syncthreads();
    // Phase 2: lanes 0..31 fold this half's 144 rows, carry held in register.
    if (tid < TO) {
      float c = carry;
#pragma unroll 8
      for (int kk = 0; kk < KH; ++kk) {
        c += sP[kk][tid];                   // exact reference fold order
        sP[kk][tid] = c;
        maxc = fmaxf(maxc, fabsf(c));
      }
      carry = c;
    }
    __syncthreads();
    // Phase 3: coalesced write-out (rows of 32 consecutive outi).
    for (int kk = s; kk < KH; kk += 8)
      cws[(uint32_t)(kbase + kk) * NOUT + outi0 + (uint32_t)o] = sP[kk][o];
    __syncthreads();                        // next half overwrites sP
  }
  // maxc lives in lanes 0..31 of wave 0; lanes 32..63 hold 0 -> full-wave reduce.
  if (tid < 64) {
#pragma unroll
    for (int off = 32; off > 0; off >>= 1)
      maxc = fmaxf(maxc, __shfl_down(maxc, off));
    if (tid == 0) atomicMax(maxc_bits, __float_as_uint(maxc));
  }
}

// ---------- k_fi2split: FI2 on c, in-block k-split, 8-way cipher batching ----
__global__ __launch_bounds__(256) void k_fi2split(const float* __restrict__ cws,
                                                  const unsigned int* __restrict__ scal,
                                                  unsigned int* __restrict__ maxy_bits,
                                                  float* __restrict__ yout,
                                                  uint32_t ku0, uint32_t ku1,
                                                  uint32_t kp0, uint32_t kp1) {
#pragma clang fp contract(off)
  __shared__ float sE[KG][64];
  __shared__ float sYs[64];
  int tid = threadIdx.x;
  int lane = tid & 63;
  int kg = tid >> 6;                               // 0..3
  uint32_t outi = blockIdx.x * 64u + (uint32_t)lane;   // 3136*64 = NOUT exact
  float scale_c = __uint_as_float(scal[2]) / 127.0f + 1e-12f;
  int ks = (kg == 0) ? 1 : kg * KCH;
  int ke = (kg == KG - 1) ? (KK - 1) : (kg * KCH + KCH);
  const float* cp = cws + (uint32_t)ks * NOUT + outi;
  uint32_t i0 = outi * (uint32_t)KK + (uint32_t)ks;
  float e = 0.f;
  int k = ks;
  while (k + 8 <= ke) {
    float c8[8];
    uint32_t ub[8];
#pragma unroll
    for (int j = 0; j < 8; ++j) c8[j] = cp[(uint32_t)j * NOUT];  // issue loads
#pragma unroll
    for (int j = 0; j < 8; ++j) ub[j] = rbits(ku0, ku1, i0 + (uint32_t)j);
#pragma unroll
    for (int j = 0; j < 8; ++j) {
      float cf = fi_fwd_skip(c8[j], scale_c, ub[j], kp0, kp1, i0 + (uint32_t)j);
      e += (cf - c8[j]);
    }
    cp += 8u * NOUT; i0 += 8; k += 8;
  }
  for (; k < ke; ++k) {
    float c = *cp; cp += NOUT;
    uint32_t ub = rbits(ku0, ku1, i0);
    float cf = fi_fwd_skip(c, scale_c, ub, kp0, kp1, i0);
    e += (cf - c);
    ++i0;
  }
  sE[kg][lane] = e;
  if (kg == KG - 1) {                              // k = 287 -> ys
    float c = *cp;
    uint32_t ub = rbits(ku0, ku1, i0);
    float cf = fi_fwd_skip(c, scale_c, ub, kp0, kp1, i0);
    sYs[lane] = cf;
  }
  __syncthreads();
  float maxy = 0.f;
  if (tid < 64) {
    float ee = ((sE[0][lane] + sE[1][lane]) + sE[2][lane]) + sE[3][lane];
    float y = sYs[lane] + ee;
    yout[outi] = y;
    maxy = fabsf(y);
  }
  maxy = block_max<256>(maxy);
  if (tid == 0) atomicMax(maxy_bits, __float_as_uint(maxy));
}

// ---------- fallback (small ws): fused FI1+cumsum, then recompute-FI2 ----------
__global__ __launch_bounds__(64) void k_passC_nostore(const float* __restrict__ x,
                                                      const float* __restrict__ wq,
                                                      const unsigned int* __restrict__ scal,
                                                      unsigned int* __restrict__ maxc_bits,
                                                      uint32_t ku0, uint32_t ku1,
                                                      uint32_t kp0, uint32_t kp1) {
#pragma clang fp contract(off)
  __shared__ float sW[KK];
  int co = blockIdx.y;
  for (int i = threadIdx.x; i < KK; i += 64) sW[i] = wq[co * KK + i];
  __syncthreads();
  int l = blockIdx.x * 64 + threadIdx.x;
  float maxc = 0.f;
  if (l < LL) {
    float scale_p = __uint_as_float(scal[1]) / 127.0f + 1e-12f;
    int oy = l / WW, ox = l % WW;
    uint32_t base = (uint32_t)(co * LL + l) * KK;
    float c = 0.f;
    int k = 0;
    for (int ci = 0; ci < CI; ++ci) {
      const float* xr = x + ci * LL;
#pragma unroll
      for (int di = 0; di < 3; ++di) {
        int yy = oy + di - 1;
        bool yok = (yy >= 0) && (yy < HH);
#pragma unroll
        for (int dj = 0; dj < 3; ++dj, ++k) {
          int xx = ox + dj - 1;
          float xv = (yok && xx >= 0 && xx < WW) ? xr[yy * WW + xx] : 0.f;
          float p = xv * sW[k];
          uint32_t i0 = base + (uint32_t)k;
          uint32_t ub = rbits(ku0, ku1, i0);
          c += fi_fwd_skip(p, scale_p, ub, kp0, kp1, i0);
          maxc = fmaxf(maxc, fabsf(c));
        }
      }
    }
  }
  maxc = block_max<64>(maxc);
  if (threadIdx.x == 0) atomicMax(maxc_bits, __float_as_uint(maxc));
}

__global__ __launch_bounds__(256) void k_passD_rec(const float* __restrict__ x,
                                                   const float* __restrict__ wq,
                                                   const unsigned int* __restrict__ scal,
                                                   unsigned int* __restrict__ maxy_bits,
                                                   float* __restrict__ yout,
                                                   uint32_t ku10, uint32_t ku11,
                                                   uint32_t kp10, uint32_t kp11,
                                                   uint32_t ku20, uint32_t ku21,
                                                   uint32_t kp20, uint32_t kp21) {
#pragma clang fp contract(off)
  __shared__ float sW[KK];
  int co = blockIdx.y;
  for (int i = threadIdx.x; i < KK; i += 256) sW[i] = wq[co * KK + i];
  __syncthreads();
  int l = blockIdx.x * 256 + threadIdx.x;
  float maxy = 0.f;
  if (l < LL) {
    float scale_p = __uint_as_float(scal[1]) / 127.0f + 1e-12f;
    float scale_c = __uint_as_float(scal[2]) / 127.0f + 1e-12f;
    int oy = l / WW, ox = l % WW;
    uint32_t base = (uint32_t)(co * LL + l) * KK;
    float c = 0.f, e = 0.f, ys = 0.f;
    int k = 0;
    for (int ci = 0; ci < CI; ++ci) {
      const float* xr = x + ci * LL;
#pragma unroll
      for (int di = 0; di < 3; ++di) {
        int yy = oy + di - 1;
        bool yok = (yy >= 0) && (yy < HH);
#pragma unroll
        for (int dj = 0; dj < 3; ++dj, ++k) {
          int xx = ox + dj - 1;
          float xv = (yok && xx >= 0 && xx < WW) ? xr[yy * WW + xx] : 0.f;
          float p = xv * sW[k];
          uint32_t i0 = base + (uint32_t)k;
          uint32_t ub1 = rbits(ku10, ku11, i0);
          c += fi_fwd_skip(p, scale_p, ub1, kp10, kp11, i0);
          uint32_t ub2 = rbits(ku20, ku21, i0);
          float cf = fi_fwd_skip(c, scale_c, ub2, kp20, kp21, i0);
          if (k >= 1 && k <= 286) e += (cf - c);
          if (k == 287)           ys = cf;
        }
      }
    }
    float y = ys + e;
    yout[co * LL + l] = y;
    maxy = fabsf(y);
  }
  maxy = block_max<256>(maxy);
  if (threadIdx.x == 0) atomicMax(maxy_bits, __float_as_uint(maxy));
}

// ---------- pass E: FI3 on y, in place in d_out ----------
__global__ __launch_bounds__(256) void k_passE(float* __restrict__ y,
                                               const unsigned int* __restrict__ scal,
                                               uint32_t ku0, uint32_t ku1,
                                               uint32_t kp0, uint32_t kp1) {
#pragma clang fp contract(off)
  uint32_t i = blockIdx.x * 256u + threadIdx.x;
  float scale_y = __uint_as_float(scal[3]) / 127.0f + 1e-12f;
  uint32_t ub = rbits(ku0, ku1, i);
  y[i] = fi_fwd_skip(y[i], scale_y, ub, kp0, kp1, i);
}

extern "C" void kernel_launch(void* const* d_in, const int* in_sizes, int n_in,
                              void* d_out, int out_size, void* d_ws, size_t ws_size,
                              hipStream_t stream) {
  const float* x = (const float*)d_in[0];   // (1,32,56,56)
  const float* w = (const float*)d_in[1];   // (64,32,3,3)
  float* out = (float*)d_out;               // (1,64,56,56)

  unsigned int* scal = (unsigned int*)d_ws; // [1]=max|p| [2]=max|c| [3]=max|y|
  float* wq = (float*)d_ws + 16;            // 18432 floats
  float* cws = (float*)d_ws + CWS_OFF_FLOATS;
  bool bigws = ws_size >= WS_NEED;          // constant across calls -> graph-safe

  // ---- exact JAX key derivation, partitionable threefry ----
  uint32_t K1[2], K2[2], K3[2];
  tf2x32(0u, 42u, 0u, 0u, K1[0], K1[1]);    // split(key(42), 3)
  tf2x32(0u, 42u, 0u, 1u, K2[0], K2[1]);
  tf2x32(0u, 42u, 0u, 2u, K3[0], K3[1]);
  auto derive = [](const uint32_t kk[2], uint32_t U[2], uint32_t P[2]) {
    uint32_t kA0, kA1, kB0, kB1, t0, t1;
    tf2x32(kk[0], kk[1], 0u, 0u, kA0, kA1); // split(key,2)[0] -> uniform key
    tf2x32(kk[0], kk[1], 0u, 1u, kB0, kB1); // split(key,2)[1] -> randint key
    U[0] = kA0; U[1] = kA1;
    tf2x32(kB0, kB1, 0u, 1u, t0, t1);       // randint lower-bits key
    P[0] = t0; P[1] = t1;
  };
  uint32_t U1[2],P1[2],U2[2],P2[2],U3[2],P3[2];
  derive(K1, U1, P1); derive(K2, U2, P2); derive(K3, U3, P3);

  hipMemsetAsync(d_ws, 0, 64, stream);      // zero the atomic-max slots

  k_prep<<<1, 256, 0, stream>>>(w, wq);
  k_maxp<<<KK, 256, 0, stream>>>(x, wq, scal + 1);
  if (bigws) {
    k_fi1cs<<<NOUT / TO, 256, 0, stream>>>(x, wq, scal, scal + 2, cws,
                                           U1[0], U1[1], P1[0], P1[1]);
    k_fi2split<<<3136, 256, 0, stream>>>(cws, scal, scal + 3, out,
                                         U2[0], U2[1], P2[0], P2[1]);
  } else {
    dim3 gC(49, 64);
    k_passC_nostore<<<gC, 64, 0, stream>>>(x, wq, scal, scal + 2,
                                           U1[0], U1[1], P1[0], P1[1]);
    dim3 gR(13, 64);
    k_passD_rec<<<gR, 256, 0, stream>>>(x, wq, scal, scal + 3, out,
                                        U1[0], U1[1], P1[0], P1[1],
                                        U2[0], U2[1], P2[0], P2[1]);
  }
  k_passE<<<NOUT / 256, 256, 0, stream>>>(out, scal,
                                          U3[0], U3[1], P3[0], P3[1]);
}